// Round 1
// baseline (379.841 us; speedup 1.0000x reference)
//
#include <hip/hip_runtime.h>
#include <cstdint>
#include <cstddef>

// GCN: h1 = relu(norm_agg(x@W1)+b1); h2 = relu(norm_agg(h1@W2)+b2); out = h2@Wr+br
// D_IN = D_HID = 128 fixed.

constexpr int DIM = 128;

// ---------------- degree / dinv ----------------
__global__ void k_count_deg(const int* __restrict__ dst, int* __restrict__ deg, int E) {
    int e = blockIdx.x * blockDim.x + threadIdx.x;
    if (e < E) atomicAdd(&deg[dst[e]], 1);
}

__global__ void k_dinv(const int* __restrict__ deg, float* __restrict__ dinv, int N) {
    int i = blockIdx.x * blockDim.x + threadIdx.x;
    if (i < N) dinv[i] = rsqrtf((float)deg[i] + 1.0f);
}

// ---------------- hierarchical exclusive scan of deg -> row_ptr ----------------
__global__ void k_scan1(const int* __restrict__ deg, int* __restrict__ incl,
                        int* __restrict__ bsums, int N) {
    __shared__ int s[256];
    int i = blockIdx.x * 256 + threadIdx.x;
    int v = (i < N) ? deg[i] : 0;
    s[threadIdx.x] = v;
    __syncthreads();
    for (int off = 1; off < 256; off <<= 1) {
        int t = (threadIdx.x >= off) ? s[threadIdx.x - off] : 0;
        __syncthreads();
        s[threadIdx.x] += t;
        __syncthreads();
    }
    if (i < N) incl[i] = s[threadIdx.x];
    if (threadIdx.x == 255) bsums[blockIdx.x] = s[255];
}

__global__ void k_scan2(int* __restrict__ bsums, int nb) {
    // single block of 256; nb <= 256
    __shared__ int s[256];
    int v = (threadIdx.x < nb) ? bsums[threadIdx.x] : 0;
    s[threadIdx.x] = v;
    __syncthreads();
    for (int off = 1; off < 256; off <<= 1) {
        int t = (threadIdx.x >= off) ? s[threadIdx.x - off] : 0;
        __syncthreads();
        s[threadIdx.x] += t;
        __syncthreads();
    }
    if (threadIdx.x < nb) bsums[threadIdx.x] = s[threadIdx.x] - v;  // exclusive
}

__global__ void k_scan3(const int* __restrict__ incl, const int* __restrict__ deg,
                        const int* __restrict__ bsums, int* __restrict__ row_ptr,
                        int N, int E) {
    int i = blockIdx.x * 256 + threadIdx.x;
    if (i < N) row_ptr[i] = incl[i] - deg[i] + bsums[blockIdx.x];
    if (i == 0) row_ptr[N] = E;
}

// ---------------- CSR fill ----------------
__global__ void k_fill(const int* __restrict__ src, const int* __restrict__ dst,
                       const float* __restrict__ dinv, const int* __restrict__ row_ptr,
                       int* __restrict__ cnt, int* __restrict__ col,
                       float* __restrict__ nrm, int E) {
    int e = blockIdx.x * blockDim.x + threadIdx.x;
    if (e >= E) return;
    int d = dst[e], s = src[e];
    int pos = row_ptr[d] + atomicAdd(&cnt[d], 1);
    col[pos] = s;
    nrm[pos] = dinv[s] * dinv[d];
}

// ---------------- GEMM: H = X @ W  (X [N,128], W [128,128]) ----------------
// 64 rows per block; W fully staged (64KB) + X tile (132-float padded rows, 33KB).
// 256 threads: cg = t&31 -> 4 cols, rg = t>>5 -> 8 rows. 32 acc/thread.
#define GR 64
#define SXS 132  // padded row stride (floats), 16B-aligned, breaks bank aliasing

__global__ __launch_bounds__(256) void k_gemm(const float* __restrict__ X,
                                              const float* __restrict__ W,
                                              float* __restrict__ H, int N) {
    __shared__ float sW[128 * 128];
    __shared__ float sX[GR * SXS];
    int t = threadIdx.x;
    int row0 = blockIdx.x * GR;

    {   // stage W: 4096 float4
        const float4* W4 = (const float4*)W;
        float4* sW4 = (float4*)sW;
#pragma unroll
        for (int i = 0; i < 16; i++) sW4[t + i * 256] = W4[t + i * 256];
    }
    {   // stage X tile
        int nrow = N - row0; if (nrow > GR) nrow = GR;
        const float4* X4 = (const float4*)(X + (size_t)row0 * DIM);
        float4* sX4 = (float4*)sX;
        for (int idx = t; idx < nrow * 32; idx += 256) {
            int r = idx >> 5, c = idx & 31;
            sX4[r * (SXS / 4) + c] = X4[idx];
        }
    }
    __syncthreads();

    int cg = t & 31;   // col group: cols cg*4 .. cg*4+3
    int rg = t >> 5;   // row group: rows rg*8 .. rg*8+7
    float acc[8][4];
#pragma unroll
    for (int r = 0; r < 8; r++)
#pragma unroll
        for (int c = 0; c < 4; c++) acc[r][c] = 0.f;

    const float* sWp = sW + cg * 4;
    const float* sXp = sX + (rg * 8) * SXS;

#define FMA4(xs, wv)                                  \
    acc[r][0] = fmaf((xs), (wv).x, acc[r][0]);        \
    acc[r][1] = fmaf((xs), (wv).y, acc[r][1]);        \
    acc[r][2] = fmaf((xs), (wv).z, acc[r][2]);        \
    acc[r][3] = fmaf((xs), (wv).w, acc[r][3]);

    for (int k = 0; k < 128; k += 4) {
        float4 wv0 = *(const float4*)(sWp + (k + 0) * 128);
        float4 wv1 = *(const float4*)(sWp + (k + 1) * 128);
        float4 wv2 = *(const float4*)(sWp + (k + 2) * 128);
        float4 wv3 = *(const float4*)(sWp + (k + 3) * 128);
#pragma unroll
        for (int r = 0; r < 8; r++) {
            float4 xv = *(const float4*)(sXp + r * SXS + k);
            FMA4(xv.x, wv0)
            FMA4(xv.y, wv1)
            FMA4(xv.z, wv2)
            FMA4(xv.w, wv3)
        }
    }
#undef FMA4

    int nrow = N - row0;
#pragma unroll
    for (int r = 0; r < 8; r++) {
        int rr = rg * 8 + r;
        if (rr < nrow) {
            *(float4*)(H + (size_t)(row0 + rr) * DIM + cg * 4) =
                make_float4(acc[r][0], acc[r][1], acc[r][2], acc[r][3]);
        }
    }
}

// ---------------- aggregation: one wave per dst node ----------------
// O[n] = relu( sum_{e in CSR[n]} nrm[e]*H[col[e]] + dinv[n]^2*H[n] + B )
__global__ __launch_bounds__(256) void k_agg(const float* __restrict__ H,
                                             const int* __restrict__ row_ptr,
                                             const int* __restrict__ col,
                                             const float* __restrict__ nrm,
                                             const float* __restrict__ dinv,
                                             const float* __restrict__ B,
                                             float* __restrict__ O, int N) {
    int wid = (int)(((size_t)blockIdx.x * blockDim.x + threadIdx.x) >> 6);
    int lane = threadIdx.x & 63;
    if (wid >= N) return;
    int beg = row_ptr[wid], end = row_ptr[wid + 1];
    float di = dinv[wid];
    float2 hs = *(const float2*)(H + (size_t)wid * DIM + lane * 2);
    float sl = di * di;
    float ax = sl * hs.x, ay = sl * hs.y;
    for (int e = beg; e < end; e++) {
        int s = col[e];
        float w = nrm[e];
        float2 hv = *(const float2*)(H + (size_t)s * DIM + lane * 2);
        ax = fmaf(w, hv.x, ax);
        ay = fmaf(w, hv.y, ay);
    }
    float2 b = *(const float2*)(B + lane * 2);
    ax = fmaxf(ax + b.x, 0.f);
    ay = fmaxf(ay + b.y, 0.f);
    *(float2*)(O + (size_t)wid * DIM + lane * 2) = make_float2(ax, ay);
}

// ---------------- readout: out[n] = dot(H[n], Wr) + br ----------------
__global__ __launch_bounds__(256) void k_readout(const float* __restrict__ H,
                                                 const float* __restrict__ Wr,
                                                 const float* __restrict__ br,
                                                 float* __restrict__ out, int N) {
    int wid = (int)(((size_t)blockIdx.x * blockDim.x + threadIdx.x) >> 6);
    int lane = threadIdx.x & 63;
    if (wid >= N) return;
    float2 h = *(const float2*)(H + (size_t)wid * DIM + lane * 2);
    float2 w = *(const float2*)(Wr + lane * 2);
    float v = h.x * w.x + h.y * w.y;
#pragma unroll
    for (int off = 32; off > 0; off >>= 1) v += __shfl_down(v, off, 64);
    if (lane == 0) out[wid] = v + br[0];
}

extern "C" void kernel_launch(void* const* d_in, const int* in_sizes, int n_in,
                              void* d_out, int out_size, void* d_ws, size_t ws_size,
                              hipStream_t stream) {
    const float* x  = (const float*)d_in[0];
    const int*   ei = (const int*)d_in[1];
    const float* W1 = (const float*)d_in[2];
    const float* b1 = (const float*)d_in[3];
    const float* W2 = (const float*)d_in[4];
    const float* b2 = (const float*)d_in[5];
    const float* Wr = (const float*)d_in[6];
    const float* br = (const float*)d_in[7];

    const int N = in_sizes[0] / DIM;
    const int E = in_sizes[1] / 2;
    const int* src = ei;
    const int* dst = ei + E;

    char* p = (char*)d_ws;
    auto alloc = [&](size_t bytes) -> void* {
        void* r = (void*)p;
        p += (bytes + 255) & ~(size_t)255;
        return r;
    };
    float* hA      = (float*)alloc((size_t)N * DIM * 4);
    float* hB      = (float*)alloc((size_t)N * DIM * 4);
    int*   deg     = (int*)alloc((size_t)N * 4);
    float* dinv    = (float*)alloc((size_t)N * 4);
    int*   incl    = (int*)alloc((size_t)N * 4);
    int*   bsums   = (int*)alloc(1024);
    int*   row_ptr = (int*)alloc((size_t)(N + 1) * 4);
    int*   cnt     = (int*)alloc((size_t)N * 4);
    int*   col     = (int*)alloc((size_t)E * 4);
    float* nrm     = (float*)alloc((size_t)E * 4);
    (void)ws_size; (void)n_in;

    hipMemsetAsync(deg, 0, (size_t)N * 4, stream);
    hipMemsetAsync(cnt, 0, (size_t)N * 4, stream);

    const int nbE = (E + 255) / 256;
    const int nbN = (N + 255) / 256;

    k_count_deg<<<nbE, 256, 0, stream>>>(dst, deg, E);
    k_dinv<<<nbN, 256, 0, stream>>>(deg, dinv, N);
    k_scan1<<<nbN, 256, 0, stream>>>(deg, incl, bsums, N);
    k_scan2<<<1, 256, 0, stream>>>(bsums, nbN);
    k_scan3<<<nbN, 256, 0, stream>>>(incl, deg, bsums, row_ptr, N, E);
    k_fill<<<nbE, 256, 0, stream>>>(src, dst, dinv, row_ptr, cnt, col, nrm, E);

    const int gb = (N + GR - 1) / GR;          // gemm blocks
    const int ab = (N * 64 + 255) / 256;       // wave-per-node blocks

    k_gemm<<<gb, 256, 0, stream>>>(x, W1, hA, N);
    k_agg<<<ab, 256, 0, stream>>>(hA, row_ptr, col, nrm, dinv, b1, hB, N);
    k_gemm<<<gb, 256, 0, stream>>>(hB, W2, hA, N);
    k_agg<<<ab, 256, 0, stream>>>(hA, row_ptr, col, nrm, dinv, b2, hB, N);
    k_readout<<<ab, 256, 0, stream>>>(hB, Wr, br, (float*)d_out, N);
}

// Round 2
// 314.275 us; speedup vs baseline: 1.2086x; 1.2086x over previous
//
#include <hip/hip_runtime.h>
#include <cstdint>
#include <cstddef>

// GCN: h1 = relu(norm_agg(x@W1)+b1); h2 = relu(norm_agg(h1@W2)+b2); out = h2@Wr+br
// D_IN = D_HID = 128 fixed.

constexpr int DIM = 128;

// ---------------- degree ----------------
__global__ void k_count_deg(const int* __restrict__ dst, int* __restrict__ deg, int E) {
    int e = blockIdx.x * blockDim.x + threadIdx.x;
    if (e < E) atomicAdd(&deg[dst[e]], 1);
}

// ---------------- hierarchical exclusive scan of deg -> row_ptr ----------------
__global__ void k_scan1(const int* __restrict__ deg, int* __restrict__ incl,
                        int* __restrict__ bsums, int N) {
    __shared__ int s[256];
    int i = blockIdx.x * 256 + threadIdx.x;
    int v = (i < N) ? deg[i] : 0;
    s[threadIdx.x] = v;
    __syncthreads();
    for (int off = 1; off < 256; off <<= 1) {
        int t = (threadIdx.x >= off) ? s[threadIdx.x - off] : 0;
        __syncthreads();
        s[threadIdx.x] += t;
        __syncthreads();
    }
    if (i < N) incl[i] = s[threadIdx.x];
    if (threadIdx.x == 255) bsums[blockIdx.x] = s[255];
}

__global__ void k_scan2(int* __restrict__ bsums, int nb) {
    __shared__ int s[256];
    int v = (threadIdx.x < nb) ? bsums[threadIdx.x] : 0;
    s[threadIdx.x] = v;
    __syncthreads();
    for (int off = 1; off < 256; off <<= 1) {
        int t = (threadIdx.x >= off) ? s[threadIdx.x - off] : 0;
        __syncthreads();
        s[threadIdx.x] += t;
        __syncthreads();
    }
    if (threadIdx.x < nb) bsums[threadIdx.x] = s[threadIdx.x] - v;  // exclusive
}

// scan3 + dinv fused (both need deg)
__global__ void k_scan3(const int* __restrict__ incl, const int* __restrict__ deg,
                        const int* __restrict__ bsums, int* __restrict__ row_ptr,
                        float* __restrict__ dinv, int N, int E) {
    int i = blockIdx.x * 256 + threadIdx.x;
    if (i < N) {
        int d = deg[i];
        row_ptr[i] = incl[i] - d + bsums[blockIdx.x];
        dinv[i] = rsqrtf((float)d + 1.0f);
    }
    if (i == 0) row_ptr[N] = E;
}

// ---------------- CSR fill ----------------
__global__ void k_fill(const int* __restrict__ src, const int* __restrict__ dst,
                       const float* __restrict__ dinv, const int* __restrict__ row_ptr,
                       int* __restrict__ cnt, int* __restrict__ col,
                       float* __restrict__ nrm, int E) {
    int e = blockIdx.x * blockDim.x + threadIdx.x;
    if (e >= E) return;
    int d = dst[e], s = src[e];
    int pos = row_ptr[d] + atomicAdd(&cnt[d], 1);
    col[pos] = s;
    nrm[pos] = dinv[s] * dinv[d];
}

// ---------------- GEMM: H = X @ W  (X [N,128], W [128,128]) ----------------
#define GR 64
#define SXS 132  // padded row stride (floats)

__global__ __launch_bounds__(256) void k_gemm(const float* __restrict__ X,
                                              const float* __restrict__ W,
                                              float* __restrict__ H, int N) {
    __shared__ float sW[128 * 128];
    __shared__ float sX[GR * SXS];
    int t = threadIdx.x;
    int row0 = blockIdx.x * GR;

    {   // stage W: 4096 float4
        const float4* W4 = (const float4*)W;
        float4* sW4 = (float4*)sW;
#pragma unroll
        for (int i = 0; i < 16; i++) sW4[t + i * 256] = W4[t + i * 256];
    }
    {   // stage X tile
        int nrow = N - row0; if (nrow > GR) nrow = GR;
        const float4* X4 = (const float4*)(X + (size_t)row0 * DIM);
        float4* sX4 = (float4*)sX;
        for (int idx = t; idx < nrow * 32; idx += 256) {
            int r = idx >> 5, c = idx & 31;
            sX4[r * (SXS / 4) + c] = X4[idx];
        }
    }
    __syncthreads();

    int cg = t & 31;   // cols cg*4 .. cg*4+3
    int rg = t >> 5;   // rows rg*8 .. rg*8+7
    float acc[8][4];
#pragma unroll
    for (int r = 0; r < 8; r++)
#pragma unroll
        for (int c = 0; c < 4; c++) acc[r][c] = 0.f;

    const float* sWp = sW + cg * 4;
    const float* sXp = sX + (rg * 8) * SXS;

#define FMA4(xs, wv)                                  \
    acc[r][0] = fmaf((xs), (wv).x, acc[r][0]);        \
    acc[r][1] = fmaf((xs), (wv).y, acc[r][1]);        \
    acc[r][2] = fmaf((xs), (wv).z, acc[r][2]);        \
    acc[r][3] = fmaf((xs), (wv).w, acc[r][3]);

    for (int k = 0; k < 128; k += 4) {
        float4 wv0 = *(const float4*)(sWp + (k + 0) * 128);
        float4 wv1 = *(const float4*)(sWp + (k + 1) * 128);
        float4 wv2 = *(const float4*)(sWp + (k + 2) * 128);
        float4 wv3 = *(const float4*)(sWp + (k + 3) * 128);
#pragma unroll
        for (int r = 0; r < 8; r++) {
            float4 xv = *(const float4*)(sXp + r * SXS + k);
            FMA4(xv.x, wv0)
            FMA4(xv.y, wv1)
            FMA4(xv.z, wv2)
            FMA4(xv.w, wv3)
        }
    }
#undef FMA4

    int nrow = N - row0;
#pragma unroll
    for (int r = 0; r < 8; r++) {
        int rr = rg * 8 + r;
        if (rr < nrow) {
            *(float4*)(H + (size_t)(row0 + rr) * DIM + cg * 4) =
                make_float4(acc[r][0], acc[r][1], acc[r][2], acc[r][3]);
        }
    }
}

// ---------------- aggregation: one wave per dst node ----------------
// O[n] = relu( sum_{e in CSR[n]} nrm[e]*H[col[e]] + dinv[n]^2*H[n] + B )
// Scalarized indices (wave-uniform) + 8-deep unroll for memory-level parallelism.
__global__ __launch_bounds__(256) void k_agg(const float* __restrict__ H,
                                             const int* __restrict__ row_ptr,
                                             const int* __restrict__ col,
                                             const float* __restrict__ nrm,
                                             const float* __restrict__ dinv,
                                             const float* __restrict__ B,
                                             float* __restrict__ O, int N) {
    int wid = (blockIdx.x * 256 + threadIdx.x) >> 6;
    int lane = threadIdx.x & 63;
    if (wid >= N) return;
    // wave-uniform bounds -> SGPR so col/nrm loads scalarize
    int beg = __builtin_amdgcn_readfirstlane(row_ptr[wid]);
    int end = __builtin_amdgcn_readfirstlane(row_ptr[wid + 1]);
    float di = dinv[wid];
    const float2* Hl = (const float2*)H + lane;  // row s -> Hl[s*64]
    float2 hs = Hl[(size_t)wid * 64];
    float sl = di * di;
    float ax = sl * hs.x, ay = sl * hs.y;
    float bx = 0.f, by = 0.f;

    int e = beg;
    for (; e + 8 <= end; e += 8) {
        int s0 = col[e + 0], s1 = col[e + 1], s2 = col[e + 2], s3 = col[e + 3];
        int s4 = col[e + 4], s5 = col[e + 5], s6 = col[e + 6], s7 = col[e + 7];
        float w0 = nrm[e + 0], w1 = nrm[e + 1], w2 = nrm[e + 2], w3 = nrm[e + 3];
        float w4 = nrm[e + 4], w5 = nrm[e + 5], w6 = nrm[e + 6], w7 = nrm[e + 7];
        float2 h0 = Hl[(size_t)s0 * 64];
        float2 h1 = Hl[(size_t)s1 * 64];
        float2 h2 = Hl[(size_t)s2 * 64];
        float2 h3 = Hl[(size_t)s3 * 64];
        float2 h4 = Hl[(size_t)s4 * 64];
        float2 h5 = Hl[(size_t)s5 * 64];
        float2 h6 = Hl[(size_t)s6 * 64];
        float2 h7 = Hl[(size_t)s7 * 64];
        ax = fmaf(w0, h0.x, ax); ay = fmaf(w0, h0.y, ay);
        bx = fmaf(w1, h1.x, bx); by = fmaf(w1, h1.y, by);
        ax = fmaf(w2, h2.x, ax); ay = fmaf(w2, h2.y, ay);
        bx = fmaf(w3, h3.x, bx); by = fmaf(w3, h3.y, by);
        ax = fmaf(w4, h4.x, ax); ay = fmaf(w4, h4.y, ay);
        bx = fmaf(w5, h5.x, bx); by = fmaf(w5, h5.y, by);
        ax = fmaf(w6, h6.x, ax); ay = fmaf(w6, h6.y, ay);
        bx = fmaf(w7, h7.x, bx); by = fmaf(w7, h7.y, by);
    }
    for (; e + 4 <= end; e += 4) {
        int s0 = col[e + 0], s1 = col[e + 1], s2 = col[e + 2], s3 = col[e + 3];
        float w0 = nrm[e + 0], w1 = nrm[e + 1], w2 = nrm[e + 2], w3 = nrm[e + 3];
        float2 h0 = Hl[(size_t)s0 * 64];
        float2 h1 = Hl[(size_t)s1 * 64];
        float2 h2 = Hl[(size_t)s2 * 64];
        float2 h3 = Hl[(size_t)s3 * 64];
        ax = fmaf(w0, h0.x, ax); ay = fmaf(w0, h0.y, ay);
        bx = fmaf(w1, h1.x, bx); by = fmaf(w1, h1.y, by);
        ax = fmaf(w2, h2.x, ax); ay = fmaf(w2, h2.y, ay);
        bx = fmaf(w3, h3.x, bx); by = fmaf(w3, h3.y, by);
    }
    for (; e < end; e++) {
        int s = col[e];
        float w = nrm[e];
        float2 hv = Hl[(size_t)s * 64];
        ax = fmaf(w, hv.x, ax); ay = fmaf(w, hv.y, ay);
    }
    ax += bx; ay += by;

    float2 b = *(const float2*)(B + lane * 2);
    ax = fmaxf(ax + b.x, 0.f);
    ay = fmaxf(ay + b.y, 0.f);
    *(float2*)(O + (size_t)wid * DIM + lane * 2) = make_float2(ax, ay);
}

// ---------------- readout: out[n] = dot(H[n], Wr) + br ----------------
__global__ __launch_bounds__(256) void k_readout(const float* __restrict__ H,
                                                 const float* __restrict__ Wr,
                                                 const float* __restrict__ br,
                                                 float* __restrict__ out, int N) {
    int wid = (blockIdx.x * 256 + threadIdx.x) >> 6;
    int lane = threadIdx.x & 63;
    if (wid >= N) return;
    float2 h = *(const float2*)(H + (size_t)wid * DIM + lane * 2);
    float2 w = *(const float2*)(Wr + lane * 2);
    float v = h.x * w.x + h.y * w.y;
#pragma unroll
    for (int off = 32; off > 0; off >>= 1) v += __shfl_down(v, off, 64);
    if (lane == 0) out[wid] = v + br[0];
}

extern "C" void kernel_launch(void* const* d_in, const int* in_sizes, int n_in,
                              void* d_out, int out_size, void* d_ws, size_t ws_size,
                              hipStream_t stream) {
    const float* x  = (const float*)d_in[0];
    const int*   ei = (const int*)d_in[1];
    const float* W1 = (const float*)d_in[2];
    const float* b1 = (const float*)d_in[3];
    const float* W2 = (const float*)d_in[4];
    const float* b2 = (const float*)d_in[5];
    const float* Wr = (const float*)d_in[6];
    const float* br = (const float*)d_in[7];

    const int N = in_sizes[0] / DIM;
    const int E = in_sizes[1] / 2;
    const int* src = ei;
    const int* dst = ei + E;

    char* p = (char*)d_ws;
    auto alloc = [&](size_t bytes) -> void* {
        void* r = (void*)p;
        p += (bytes + 255) & ~(size_t)255;
        return r;
    };
    float* hA      = (float*)alloc((size_t)N * DIM * 4);
    float* hB      = (float*)alloc((size_t)N * DIM * 4);
    int*   deg     = (int*)alloc((size_t)N * 4);
    float* dinv    = (float*)alloc((size_t)N * 4);
    int*   incl    = (int*)alloc((size_t)N * 4);
    int*   bsums   = (int*)alloc(1024);
    int*   row_ptr = (int*)alloc((size_t)(N + 1) * 4);
    int*   cnt     = (int*)alloc((size_t)N * 4);
    int*   col     = (int*)alloc((size_t)E * 4);
    float* nrm     = (float*)alloc((size_t)E * 4);
    (void)ws_size; (void)n_in;

    hipMemsetAsync(deg, 0, (size_t)N * 4, stream);
    hipMemsetAsync(cnt, 0, (size_t)N * 4, stream);

    const int nbE = (E + 255) / 256;
    const int nbN = (N + 255) / 256;

    k_count_deg<<<nbE, 256, 0, stream>>>(dst, deg, E);
    k_scan1<<<nbN, 256, 0, stream>>>(deg, incl, bsums, N);
    k_scan2<<<1, 256, 0, stream>>>(bsums, nbN);
    k_scan3<<<nbN, 256, 0, stream>>>(incl, deg, bsums, row_ptr, dinv, N, E);
    k_fill<<<nbE, 256, 0, stream>>>(src, dst, dinv, row_ptr, cnt, col, nrm, E);

    const int gb = (N + GR - 1) / GR;
    const int ab = (N * 64 + 255) / 256;

    k_gemm<<<gb, 256, 0, stream>>>(x, W1, hA, N);
    k_agg<<<ab, 256, 0, stream>>>(hA, row_ptr, col, nrm, dinv, b1, hB, N);
    k_gemm<<<gb, 256, 0, stream>>>(hB, W2, hA, N);
    k_agg<<<ab, 256, 0, stream>>>(hA, row_ptr, col, nrm, dinv, b2, hB, N);
    k_readout<<<ab, 256, 0, stream>>>(hB, Wr, br, (float*)d_out, N);
}

// Round 3
// 284.863 us; speedup vs baseline: 1.3334x; 1.1032x over previous
//
#include <hip/hip_runtime.h>
#include <cstdint>
#include <cstddef>

// GCN: h1 = relu(norm_agg(x@W1)+b1); h2 = relu(norm_agg(h1@W2)+b2); out = h2@Wr+br
// D_IN = D_HID = 128 fixed.

constexpr int DIM = 128;

// ---------------- degree ----------------
__global__ void k_count_deg(const int* __restrict__ dst, int* __restrict__ deg, int E) {
    int e = blockIdx.x * blockDim.x + threadIdx.x;
    if (e < E) atomicAdd(&deg[dst[e]], 1);
}

// ---------------- hierarchical exclusive scan of deg -> row_ptr ----------------
__global__ void k_scan1(const int* __restrict__ deg, int* __restrict__ incl,
                        int* __restrict__ bsums, int N) {
    __shared__ int s[256];
    int i = blockIdx.x * 256 + threadIdx.x;
    int v = (i < N) ? deg[i] : 0;
    s[threadIdx.x] = v;
    __syncthreads();
    for (int off = 1; off < 256; off <<= 1) {
        int t = (threadIdx.x >= off) ? s[threadIdx.x - off] : 0;
        __syncthreads();
        s[threadIdx.x] += t;
        __syncthreads();
    }
    if (i < N) incl[i] = s[threadIdx.x];
    if (threadIdx.x == 255) bsums[blockIdx.x] = s[255];
}

__global__ void k_scan2(int* __restrict__ bsums, int nb) {
    __shared__ int s[256];
    int v = (threadIdx.x < nb) ? bsums[threadIdx.x] : 0;
    s[threadIdx.x] = v;
    __syncthreads();
    for (int off = 1; off < 256; off <<= 1) {
        int t = (threadIdx.x >= off) ? s[threadIdx.x - off] : 0;
        __syncthreads();
        s[threadIdx.x] += t;
        __syncthreads();
    }
    if (threadIdx.x < nb) bsums[threadIdx.x] = s[threadIdx.x] - v;  // exclusive
}

// scan3 + dinv + cursor init fused
__global__ void k_scan3(const int* __restrict__ incl, const int* __restrict__ deg,
                        const int* __restrict__ bsums, int* __restrict__ row_ptr,
                        int* __restrict__ cursor, float* __restrict__ dinv,
                        int N, int E) {
    int i = blockIdx.x * 256 + threadIdx.x;
    if (i < N) {
        int d = deg[i];
        int rp = incl[i] - d + bsums[blockIdx.x];
        row_ptr[i] = rp;
        cursor[i] = rp;
        dinv[i] = rsqrtf((float)d + 1.0f);
    }
    if (i == 0) row_ptr[N] = E;
}

// ---------------- CSR fill: packed (col, nrm) -> one 8B scatter per edge ----
__global__ void k_fill(const int* __restrict__ src, const int* __restrict__ dst,
                       const float* __restrict__ dinv, int* __restrict__ cursor,
                       int2* __restrict__ colnrm, int E) {
    int e = blockIdx.x * blockDim.x + threadIdx.x;
    if (e >= E) return;
    int d = dst[e], s = src[e];
    int pos = atomicAdd(&cursor[d], 1);
    colnrm[pos] = make_int2(s, __float_as_int(dinv[s] * dinv[d]));
}

// ---------------- GEMM: H = X @ W  (X [N,128], W [128,128]) ----------------
// 64 rows/block, 256 threads. W staged in 4 K-quarters of 16KB -> LDS total
// 49.8KB -> 3 blocks/CU (12 waves, 3/SIMD) instead of 1 block (4 waves).
#define GR 64
#define SXS 132   // padded X row stride (floats)
#define KB 32     // K-quarter

__global__ __launch_bounds__(256) void k_gemm(const float* __restrict__ X,
                                              const float* __restrict__ W,
                                              float* __restrict__ H, int N) {
    __shared__ float sW[KB * 128];    // 16KB
    __shared__ float sX[GR * SXS];    // 33.8KB
    int t = threadIdx.x;
    int row0 = blockIdx.x * GR;
    int nrow = N - row0; if (nrow > GR) nrow = GR;

    {   // stage X tile once
        const float4* X4 = (const float4*)(X + (size_t)row0 * DIM);
        float4* sX4 = (float4*)sX;
        for (int idx = t; idx < nrow * 32; idx += 256) {
            int r = idx >> 5, c = idx & 31;
            sX4[r * (SXS / 4) + c] = X4[idx];
        }
    }

    int cg = t & 31;   // cols cg*4 .. cg*4+3
    int rg = t >> 5;   // rows rg*8 .. rg*8+7
    float acc[8][4];
#pragma unroll
    for (int r = 0; r < 8; r++)
#pragma unroll
        for (int c = 0; c < 4; c++) acc[r][c] = 0.f;

    const float* sWp = sW + cg * 4;
    const float* sXbase = sX + (rg * 8) * SXS;

#define FMA4(xs, wv)                                  \
    acc[r][0] = fmaf((xs), (wv).x, acc[r][0]);        \
    acc[r][1] = fmaf((xs), (wv).y, acc[r][1]);        \
    acc[r][2] = fmaf((xs), (wv).z, acc[r][2]);        \
    acc[r][3] = fmaf((xs), (wv).w, acc[r][3]);

    for (int kb = 0; kb < 128; kb += KB) {
        __syncthreads();  // previous quarter fully consumed (also covers sX on kb=0)
        {   // stage W rows kb..kb+KB-1 : KB*128 floats = KB*32 float4
            const float4* W4 = (const float4*)(W + (size_t)kb * 128);
            float4* sW4 = (float4*)sW;
#pragma unroll
            for (int i = 0; i < (KB * 32) / 256; i++) sW4[t + i * 256] = W4[t + i * 256];
        }
        __syncthreads();
        const float* sXp = sXbase + kb;
        for (int k = 0; k < KB; k += 4) {
            float4 wv0 = *(const float4*)(sWp + (k + 0) * 128);
            float4 wv1 = *(const float4*)(sWp + (k + 1) * 128);
            float4 wv2 = *(const float4*)(sWp + (k + 2) * 128);
            float4 wv3 = *(const float4*)(sWp + (k + 3) * 128);
#pragma unroll
            for (int r = 0; r < 8; r++) {
                float4 xv = *(const float4*)(sXp + r * SXS + k);
                FMA4(xv.x, wv0)
                FMA4(xv.y, wv1)
                FMA4(xv.z, wv2)
                FMA4(xv.w, wv3)
            }
        }
    }
#undef FMA4

#pragma unroll
    for (int r = 0; r < 8; r++) {
        int rr = rg * 8 + r;
        if (rr < nrow) {
            *(float4*)(H + (size_t)(row0 + rr) * DIM + cg * 4) =
                make_float4(acc[r][0], acc[r][1], acc[r][2], acc[r][3]);
        }
    }
}

// ---------------- aggregation: one wave per dst node ----------------
// O[n] = relu( sum_{e in CSR[n]} nrm[e]*H[col[e]] + dinv[n]^2*H[n] + B )
__global__ __launch_bounds__(256) void k_agg(const float* __restrict__ H,
                                             const int* __restrict__ row_ptr,
                                             const int2* __restrict__ CN,
                                             const float* __restrict__ dinv,
                                             const float* __restrict__ B,
                                             float* __restrict__ O, int N) {
    int wid = (blockIdx.x * 256 + threadIdx.x) >> 6;
    int lane = threadIdx.x & 63;
    if (wid >= N) return;
    int beg = __builtin_amdgcn_readfirstlane(row_ptr[wid]);
    int end = __builtin_amdgcn_readfirstlane(row_ptr[wid + 1]);
    float di = dinv[wid];
    const float2* Hl = (const float2*)H + lane;  // row s -> Hl[s*64]
    float2 hs = Hl[(size_t)wid * 64];
    float sl = di * di;
    float ax = sl * hs.x, ay = sl * hs.y;
    float bx = 0.f, by = 0.f;

    int e = beg;
    for (; e + 8 <= end; e += 8) {
        int2 c0 = CN[e + 0], c1 = CN[e + 1], c2 = CN[e + 2], c3 = CN[e + 3];
        int2 c4 = CN[e + 4], c5 = CN[e + 5], c6 = CN[e + 6], c7 = CN[e + 7];
        float2 h0 = Hl[(size_t)c0.x * 64];
        float2 h1 = Hl[(size_t)c1.x * 64];
        float2 h2 = Hl[(size_t)c2.x * 64];
        float2 h3 = Hl[(size_t)c3.x * 64];
        float2 h4 = Hl[(size_t)c4.x * 64];
        float2 h5 = Hl[(size_t)c5.x * 64];
        float2 h6 = Hl[(size_t)c6.x * 64];
        float2 h7 = Hl[(size_t)c7.x * 64];
        float w0 = __int_as_float(c0.y), w1 = __int_as_float(c1.y);
        float w2 = __int_as_float(c2.y), w3 = __int_as_float(c3.y);
        float w4 = __int_as_float(c4.y), w5 = __int_as_float(c5.y);
        float w6 = __int_as_float(c6.y), w7 = __int_as_float(c7.y);
        ax = fmaf(w0, h0.x, ax); ay = fmaf(w0, h0.y, ay);
        bx = fmaf(w1, h1.x, bx); by = fmaf(w1, h1.y, by);
        ax = fmaf(w2, h2.x, ax); ay = fmaf(w2, h2.y, ay);
        bx = fmaf(w3, h3.x, bx); by = fmaf(w3, h3.y, by);
        ax = fmaf(w4, h4.x, ax); ay = fmaf(w4, h4.y, ay);
        bx = fmaf(w5, h5.x, bx); by = fmaf(w5, h5.y, by);
        ax = fmaf(w6, h6.x, ax); ay = fmaf(w6, h6.y, ay);
        bx = fmaf(w7, h7.x, bx); by = fmaf(w7, h7.y, by);
    }
    for (; e + 4 <= end; e += 4) {
        int2 c0 = CN[e + 0], c1 = CN[e + 1], c2 = CN[e + 2], c3 = CN[e + 3];
        float2 h0 = Hl[(size_t)c0.x * 64];
        float2 h1 = Hl[(size_t)c1.x * 64];
        float2 h2 = Hl[(size_t)c2.x * 64];
        float2 h3 = Hl[(size_t)c3.x * 64];
        float w0 = __int_as_float(c0.y), w1 = __int_as_float(c1.y);
        float w2 = __int_as_float(c2.y), w3 = __int_as_float(c3.y);
        ax = fmaf(w0, h0.x, ax); ay = fmaf(w0, h0.y, ay);
        bx = fmaf(w1, h1.x, bx); by = fmaf(w1, h1.y, by);
        ax = fmaf(w2, h2.x, ax); ay = fmaf(w2, h2.y, ay);
        bx = fmaf(w3, h3.x, bx); by = fmaf(w3, h3.y, by);
    }
    for (; e < end; e++) {
        int2 c = CN[e];
        float w = __int_as_float(c.y);
        float2 hv = Hl[(size_t)c.x * 64];
        ax = fmaf(w, hv.x, ax); ay = fmaf(w, hv.y, ay);
    }
    ax += bx; ay += by;

    float2 b = *(const float2*)(B + lane * 2);
    ax = fmaxf(ax + b.x, 0.f);
    ay = fmaxf(ay + b.y, 0.f);
    *(float2*)(O + (size_t)wid * DIM + lane * 2) = make_float2(ax, ay);
}

// ---------------- readout: out[n] = dot(H[n], Wr) + br ----------------
__global__ __launch_bounds__(256) void k_readout(const float* __restrict__ H,
                                                 const float* __restrict__ Wr,
                                                 const float* __restrict__ br,
                                                 float* __restrict__ out, int N) {
    int wid = (blockIdx.x * 256 + threadIdx.x) >> 6;
    int lane = threadIdx.x & 63;
    if (wid >= N) return;
    float2 h = *(const float2*)(H + (size_t)wid * DIM + lane * 2);
    float2 w = *(const float2*)(Wr + lane * 2);
    float v = h.x * w.x + h.y * w.y;
#pragma unroll
    for (int off = 32; off > 0; off >>= 1) v += __shfl_down(v, off, 64);
    if (lane == 0) out[wid] = v + br[0];
}

extern "C" void kernel_launch(void* const* d_in, const int* in_sizes, int n_in,
                              void* d_out, int out_size, void* d_ws, size_t ws_size,
                              hipStream_t stream) {
    const float* x  = (const float*)d_in[0];
    const int*   ei = (const int*)d_in[1];
    const float* W1 = (const float*)d_in[2];
    const float* b1 = (const float*)d_in[3];
    const float* W2 = (const float*)d_in[4];
    const float* b2 = (const float*)d_in[5];
    const float* Wr = (const float*)d_in[6];
    const float* br = (const float*)d_in[7];

    const int N = in_sizes[0] / DIM;
    const int E = in_sizes[1] / 2;
    const int* src = ei;
    const int* dst = ei + E;

    char* p = (char*)d_ws;
    auto alloc = [&](size_t bytes) -> void* {
        void* r = (void*)p;
        p += (bytes + 255) & ~(size_t)255;
        return r;
    };
    float* hA      = (float*)alloc((size_t)N * DIM * 4);
    float* hB      = (float*)alloc((size_t)N * DIM * 4);
    int*   deg     = (int*)alloc((size_t)N * 4);
    float* dinv    = (float*)alloc((size_t)N * 4);
    int*   incl    = (int*)alloc((size_t)N * 4);
    int*   bsums   = (int*)alloc(1024);
    int*   row_ptr = (int*)alloc((size_t)(N + 1) * 4);
    int*   cursor  = (int*)alloc((size_t)N * 4);
    int2*  colnrm  = (int2*)alloc((size_t)E * 8);
    (void)ws_size; (void)n_in;

    hipMemsetAsync(deg, 0, (size_t)N * 4, stream);

    const int nbE = (E + 255) / 256;
    const int nbN = (N + 255) / 256;

    k_count_deg<<<nbE, 256, 0, stream>>>(dst, deg, E);
    k_scan1<<<nbN, 256, 0, stream>>>(deg, incl, bsums, N);
    k_scan2<<<1, 256, 0, stream>>>(bsums, nbN);
    k_scan3<<<nbN, 256, 0, stream>>>(incl, deg, bsums, row_ptr, cursor, dinv, N, E);
    k_fill<<<nbE, 256, 0, stream>>>(src, dst, dinv, cursor, colnrm, E);

    const int gb = (N + GR - 1) / GR;
    const int ab = (N * 64 + 255) / 256;

    k_gemm<<<gb, 256, 0, stream>>>(x, W1, hA, N);
    k_agg<<<ab, 256, 0, stream>>>(hA, row_ptr, colnrm, dinv, b1, hB, N);
    k_gemm<<<gb, 256, 0, stream>>>(hB, W2, hA, N);
    k_agg<<<ab, 256, 0, stream>>>(hA, row_ptr, colnrm, dinv, b2, hB, N);
    k_readout<<<ab, 256, 0, stream>>>(hB, Wr, br, (float*)d_out, N);
}

// Round 4
// 225.135 us; speedup vs baseline: 1.6872x; 1.2653x over previous
//
#include <hip/hip_runtime.h>
#include <hip/hip_fp16.h>
#include <cstdint>
#include <cstddef>

// GCN refold: H'_l = dinv * (X_l @ W_l)  (fp16, row-major half2-packed)
//   layer out[d] = relu( dinv[d] * (sum_e H'[src_e] + H'[d]) + b )
// Readout fused into second aggregation.

constexpr int DIM = 128;

// ---------------- degree ----------------
__global__ void k_count_deg(const int* __restrict__ dst, int* __restrict__ deg, int E) {
    int e = blockIdx.x * blockDim.x + threadIdx.x;
    if (e < E) atomicAdd(&deg[dst[e]], 1);
}

// ---------------- hierarchical exclusive scan of deg -> row_ptr ----------------
__global__ void k_scan1(const int* __restrict__ deg, int* __restrict__ incl,
                        int* __restrict__ bsums, int N) {
    __shared__ int s[256];
    int i = blockIdx.x * 256 + threadIdx.x;
    int v = (i < N) ? deg[i] : 0;
    s[threadIdx.x] = v;
    __syncthreads();
    for (int off = 1; off < 256; off <<= 1) {
        int t = (threadIdx.x >= off) ? s[threadIdx.x - off] : 0;
        __syncthreads();
        s[threadIdx.x] += t;
        __syncthreads();
    }
    if (i < N) incl[i] = s[threadIdx.x];
    if (threadIdx.x == 255) bsums[blockIdx.x] = s[255];
}

__global__ void k_scan2(int* __restrict__ bsums, int nb) {
    __shared__ int s[256];
    int v = (threadIdx.x < nb) ? bsums[threadIdx.x] : 0;
    s[threadIdx.x] = v;
    __syncthreads();
    for (int off = 1; off < 256; off <<= 1) {
        int t = (threadIdx.x >= off) ? s[threadIdx.x - off] : 0;
        __syncthreads();
        s[threadIdx.x] += t;
        __syncthreads();
    }
    if (threadIdx.x < nb) bsums[threadIdx.x] = s[threadIdx.x] - v;  // exclusive
}

// scan3 + dinv + cursor init fused
__global__ void k_scan3(const int* __restrict__ incl, const int* __restrict__ deg,
                        const int* __restrict__ bsums, int* __restrict__ row_ptr,
                        int* __restrict__ cursor, float* __restrict__ dinv,
                        int N, int E) {
    int i = blockIdx.x * 256 + threadIdx.x;
    if (i < N) {
        int d = deg[i];
        int rp = incl[i] - d + bsums[blockIdx.x];
        row_ptr[i] = rp;
        cursor[i] = rp;
        dinv[i] = rsqrtf((float)d + 1.0f);
    }
    if (i == 0) row_ptr[N] = E;
}

// ---------------- CSR fill: col only, 4B scatter per edge ----------------
__global__ void k_fill(const int* __restrict__ src, const int* __restrict__ dst,
                       int* __restrict__ cursor, int* __restrict__ colo, int E) {
    int e = blockIdx.x * blockDim.x + threadIdx.x;
    if (e >= E) return;
    int d = dst[e];
    int pos = atomicAdd(&cursor[d], 1);
    colo[pos] = src[e];
}

// ---------------- GEMM: H' = dinv * (X @ W), fp16 out -------------------
// 64 rows/block, 256 threads, W staged in 4 K-quarters (16KB) + X tile (33.8KB).
#define GR 64
#define SXS 132   // padded X row stride (floats)
#define KB 32     // K-quarter

__global__ __launch_bounds__(256) void k_gemm(const float* __restrict__ X,
                                              const float* __restrict__ W,
                                              const float* __restrict__ dinv,
                                              __half2* __restrict__ Hh, int N) {
    __shared__ float sW[KB * 128];    // 16KB
    __shared__ float sX[GR * SXS];    // 33.8KB
    int t = threadIdx.x;
    int row0 = blockIdx.x * GR;
    int nrow = N - row0; if (nrow > GR) nrow = GR;

    {   // stage X tile once
        const float4* X4 = (const float4*)(X + (size_t)row0 * DIM);
        float4* sX4 = (float4*)sX;
        for (int idx = t; idx < nrow * 32; idx += 256) {
            int r = idx >> 5, c = idx & 31;
            sX4[r * (SXS / 4) + c] = X4[idx];
        }
    }

    int cg = t & 31;   // cols cg*4 .. cg*4+3
    int rg = t >> 5;   // rows rg*8 .. rg*8+7
    float acc[8][4];
#pragma unroll
    for (int r = 0; r < 8; r++)
#pragma unroll
        for (int c = 0; c < 4; c++) acc[r][c] = 0.f;

    const float* sWp = sW + cg * 4;
    const float* sXbase = sX + (rg * 8) * SXS;

#define FMA4(xs, wv)                                  \
    acc[r][0] = fmaf((xs), (wv).x, acc[r][0]);        \
    acc[r][1] = fmaf((xs), (wv).y, acc[r][1]);        \
    acc[r][2] = fmaf((xs), (wv).z, acc[r][2]);        \
    acc[r][3] = fmaf((xs), (wv).w, acc[r][3]);

    for (int kb = 0; kb < 128; kb += KB) {
        __syncthreads();
        {   // stage W rows kb..kb+KB-1
            const float4* W4 = (const float4*)(W + (size_t)kb * 128);
            float4* sW4 = (float4*)sW;
#pragma unroll
            for (int i = 0; i < (KB * 32) / 256; i++) sW4[t + i * 256] = W4[t + i * 256];
        }
        __syncthreads();
        const float* sXp = sXbase + kb;
        for (int k = 0; k < KB; k += 4) {
            float4 wv0 = *(const float4*)(sWp + (k + 0) * 128);
            float4 wv1 = *(const float4*)(sWp + (k + 1) * 128);
            float4 wv2 = *(const float4*)(sWp + (k + 2) * 128);
            float4 wv3 = *(const float4*)(sWp + (k + 3) * 128);
#pragma unroll
            for (int r = 0; r < 8; r++) {
                float4 xv = *(const float4*)(sXp + r * SXS + k);
                FMA4(xv.x, wv0)
                FMA4(xv.y, wv1)
                FMA4(xv.z, wv2)
                FMA4(xv.w, wv3)
            }
        }
    }
#undef FMA4

#pragma unroll
    for (int r = 0; r < 8; r++) {
        int rr = rg * 8 + r;
        if (rr < nrow) {
            float di = dinv[row0 + rr];
            union { __half2 h[2]; uint2 u; } pk;
            pk.h[0] = __floats2half2_rn(acc[r][0] * di, acc[r][1] * di);
            pk.h[1] = __floats2half2_rn(acc[r][2] * di, acc[r][3] * di);
            *(uint2*)(Hh + (size_t)(row0 + rr) * 64 + cg * 2) = pk.u;
        }
    }
}

// ---------------- aggregation core: one wave per dst node ----------------
// returns pre-activation row slice (2 cols per lane): dinv[d]*(sum+self)+bias
__device__ __forceinline__ float2 agg_row(const __half2* __restrict__ Hh,
                                          const int* __restrict__ row_ptr,
                                          const int* __restrict__ col,
                                          const float* __restrict__ dinv,
                                          const float* __restrict__ B,
                                          int wid, int lane) {
    int beg = __builtin_amdgcn_readfirstlane(row_ptr[wid]);
    int end = __builtin_amdgcn_readfirstlane(row_ptr[wid + 1]);
    const __half2* Hl = Hh + lane;  // row s -> Hl[s*64]
    float2 s0f = __half22float2(Hl[(size_t)wid * 64]);  // self (H'[d])
    float ax = s0f.x, ay = s0f.y;
    float bx = 0.f, by = 0.f, cx = 0.f, cy = 0.f, dx = 0.f, dy = 0.f;

    int e = beg;
    for (; e + 8 <= end; e += 8) {
        int s0 = col[e + 0], s1 = col[e + 1], s2 = col[e + 2], s3 = col[e + 3];
        int s4 = col[e + 4], s5 = col[e + 5], s6 = col[e + 6], s7 = col[e + 7];
        __half2 g0 = Hl[(size_t)s0 * 64];
        __half2 g1 = Hl[(size_t)s1 * 64];
        __half2 g2 = Hl[(size_t)s2 * 64];
        __half2 g3 = Hl[(size_t)s3 * 64];
        __half2 g4 = Hl[(size_t)s4 * 64];
        __half2 g5 = Hl[(size_t)s5 * 64];
        __half2 g6 = Hl[(size_t)s6 * 64];
        __half2 g7 = Hl[(size_t)s7 * 64];
        float2 f0 = __half22float2(g0), f1 = __half22float2(g1);
        float2 f2 = __half22float2(g2), f3 = __half22float2(g3);
        float2 f4 = __half22float2(g4), f5 = __half22float2(g5);
        float2 f6 = __half22float2(g6), f7 = __half22float2(g7);
        ax += f0.x; ay += f0.y;  bx += f1.x; by += f1.y;
        cx += f2.x; cy += f2.y;  dx += f3.x; dy += f3.y;
        ax += f4.x; ay += f4.y;  bx += f5.x; by += f5.y;
        cx += f6.x; cy += f6.y;  dx += f7.x; dy += f7.y;
    }
    for (; e + 4 <= end; e += 4) {
        int s0 = col[e + 0], s1 = col[e + 1], s2 = col[e + 2], s3 = col[e + 3];
        __half2 g0 = Hl[(size_t)s0 * 64];
        __half2 g1 = Hl[(size_t)s1 * 64];
        __half2 g2 = Hl[(size_t)s2 * 64];
        __half2 g3 = Hl[(size_t)s3 * 64];
        float2 f0 = __half22float2(g0), f1 = __half22float2(g1);
        float2 f2 = __half22float2(g2), f3 = __half22float2(g3);
        ax += f0.x; ay += f0.y;  bx += f1.x; by += f1.y;
        cx += f2.x; cy += f2.y;  dx += f3.x; dy += f3.y;
    }
    for (; e < end; e++) {
        float2 f = __half22float2(Hl[(size_t)col[e] * 64]);
        ax += f.x; ay += f.y;
    }
    ax += bx + cx + dx;
    ay += by + cy + dy;

    float di = dinv[wid];
    float2 b = *(const float2*)(B + lane * 2);
    return make_float2(fmaf(di, ax, b.x), fmaf(di, ay, b.y));
}

// layer-1: write relu'd fp32 row
__global__ __launch_bounds__(256) void k_agg(const __half2* __restrict__ Hh,
                                             const int* __restrict__ row_ptr,
                                             const int* __restrict__ col,
                                             const float* __restrict__ dinv,
                                             const float* __restrict__ B,
                                             float* __restrict__ O, int N) {
    int wid = (blockIdx.x * 256 + threadIdx.x) >> 6;
    int lane = threadIdx.x & 63;
    if (wid >= N) return;
    float2 r = agg_row(Hh, row_ptr, col, dinv, B, wid, lane);
    r.x = fmaxf(r.x, 0.f);
    r.y = fmaxf(r.y, 0.f);
    *(float2*)(O + (size_t)wid * DIM + lane * 2) = r;
}

// layer-2 + readout fused: out[n] = dot(relu(row), Wr) + br
__global__ __launch_bounds__(256) void k_agg_out(const __half2* __restrict__ Hh,
                                                 const int* __restrict__ row_ptr,
                                                 const int* __restrict__ col,
                                                 const float* __restrict__ dinv,
                                                 const float* __restrict__ B,
                                                 const float* __restrict__ Wr,
                                                 const float* __restrict__ br,
                                                 float* __restrict__ out, int N) {
    int wid = (blockIdx.x * 256 + threadIdx.x) >> 6;
    int lane = threadIdx.x & 63;
    if (wid >= N) return;
    float2 r = agg_row(Hh, row_ptr, col, dinv, B, wid, lane);
    float2 w = *(const float2*)(Wr + lane * 2);
    float v = fmaxf(r.x, 0.f) * w.x + fmaxf(r.y, 0.f) * w.y;
#pragma unroll
    for (int off = 32; off > 0; off >>= 1) v += __shfl_down(v, off, 64);
    if (lane == 0) out[wid] = v + br[0];
}

extern "C" void kernel_launch(void* const* d_in, const int* in_sizes, int n_in,
                              void* d_out, int out_size, void* d_ws, size_t ws_size,
                              hipStream_t stream) {
    const float* x  = (const float*)d_in[0];
    const int*   ei = (const int*)d_in[1];
    const float* W1 = (const float*)d_in[2];
    const float* b1 = (const float*)d_in[3];
    const float* W2 = (const float*)d_in[4];
    const float* b2 = (const float*)d_in[5];
    const float* Wr = (const float*)d_in[6];
    const float* br = (const float*)d_in[7];

    const int N = in_sizes[0] / DIM;
    const int E = in_sizes[1] / 2;
    const int* src = ei;
    const int* dst = ei + E;

    char* p = (char*)d_ws;
    auto alloc = [&](size_t bytes) -> void* {
        void* r = (void*)p;
        p += (bytes + 255) & ~(size_t)255;
        return r;
    };
    __half2* Hh    = (__half2*)alloc((size_t)N * DIM * 2);  // fp16 H'
    float* A1      = (float*)alloc((size_t)N * DIM * 4);    // layer-1 output fp32
    int*   deg     = (int*)alloc((size_t)N * 4);
    float* dinv    = (float*)alloc((size_t)N * 4);
    int*   incl    = (int*)alloc((size_t)N * 4);
    int*   bsums   = (int*)alloc(1024);
    int*   row_ptr = (int*)alloc((size_t)(N + 1) * 4);
    int*   cursor  = (int*)alloc((size_t)N * 4);
    int*   colo    = (int*)alloc((size_t)E * 4);
    (void)ws_size; (void)n_in;

    hipMemsetAsync(deg, 0, (size_t)N * 4, stream);

    const int nbE = (E + 255) / 256;
    const int nbN = (N + 255) / 256;

    k_count_deg<<<nbE, 256, 0, stream>>>(dst, deg, E);
    k_scan1<<<nbN, 256, 0, stream>>>(deg, incl, bsums, N);
    k_scan2<<<1, 256, 0, stream>>>(bsums, nbN);
    k_scan3<<<nbN, 256, 0, stream>>>(incl, deg, bsums, row_ptr, cursor, dinv, N, E);
    k_fill<<<nbE, 256, 0, stream>>>(src, dst, cursor, colo, E);

    const int gb = (N + GR - 1) / GR;
    const int ab = (N * 64 + 255) / 256;

    k_gemm<<<gb, 256, 0, stream>>>(x, W1, dinv, Hh, N);
    k_agg<<<ab, 256, 0, stream>>>(Hh, row_ptr, colo, dinv, b1, A1, N);
    k_gemm<<<gb, 256, 0, stream>>>(A1, W2, dinv, Hh, N);
    k_agg_out<<<ab, 256, 0, stream>>>(Hh, row_ptr, colo, dinv, b2, Wr, br,
                                      (float*)d_out, N);
}

// Round 5
// 174.787 us; speedup vs baseline: 2.1732x; 1.2881x over previous
//
#include <hip/hip_runtime.h>
#include <hip/hip_fp16.h>
#include <cstdint>
#include <cstddef>

// GCN refold: H'_l = dinv * (X_l @ W_l)  (fp16, row-major half2-packed)
//   layer out[d] = relu( dinv[d] * (sum_e H'[src_e] + H'[d]) + b )
// CSR build via 64-node buckets: hist -> bucket scan -> binned pairs ->
// per-bucket fill (deg/row_ptr/dinv/col all from one kernel, LDS-local scatter).
// Requires N < 65536 (pack (dst<<16)|src in 32 bits). N = 50000 here.

constexpr int DIM = 128;
#define BSH 6                 // 64 nodes per bucket
#define BIN_EPT 13            // edges per thread in k_bin

// ---------------- bucket histogram (LDS-privatized) ----------------
__global__ __launch_bounds__(256) void k_hist(const int* __restrict__ dst,
                                              int* __restrict__ bcount, int E, int nb) {
    __shared__ int h[1024];
    for (int i = threadIdx.x; i < nb; i += 256) h[i] = 0;
    __syncthreads();
    int stride = gridDim.x * 256;
    for (int e = blockIdx.x * 256 + threadIdx.x; e < E; e += stride)
        atomicAdd(&h[dst[e] >> BSH], 1);
    __syncthreads();
    for (int i = threadIdx.x; i < nb; i += 256) {
        int c = h[i];
        if (c) atomicAdd(&bcount[i], c);
    }
}

// ---------------- bucket exclusive scan (single block) ----------------
__global__ __launch_bounds__(1024) void k_bscan(const int* __restrict__ bcount,
                                                int* __restrict__ bptr,
                                                int* __restrict__ bcur, int nb, int E) {
    __shared__ int s[1024];
    int t = threadIdx.x;
    int v = (t < nb) ? bcount[t] : 0;
    s[t] = v;
    __syncthreads();
    for (int off = 1; off < 1024; off <<= 1) {
        int u = (t >= off) ? s[t - off] : 0;
        __syncthreads();
        s[t] += u;
        __syncthreads();
    }
    if (t < nb) { int ex = s[t] - v; bptr[t] = ex; bcur[t] = ex; }
    if (t == 0) bptr[nb] = E;
}

// ---------------- bin edges into bucket runs (block-level reservation) ----
__global__ __launch_bounds__(256) void k_bin(const int* __restrict__ src,
                                             const int* __restrict__ dst,
                                             int* __restrict__ bcur,
                                             unsigned* __restrict__ pairs,
                                             int E, int nb) {
    __shared__ int h[1024];     // local counts
    __shared__ int base[1024];  // reserved cursors
    for (int i = threadIdx.x; i < nb; i += 256) h[i] = 0;
    __syncthreads();

    int e0 = blockIdx.x * 256 * BIN_EPT;
    unsigned u[BIN_EPT];
    int cnt = 0;
#pragma unroll
    for (int j = 0; j < BIN_EPT; j++) {
        int e = e0 + j * 256 + threadIdx.x;
        if (e < E) {
            int d = dst[e];
            u[j] = ((unsigned)d << 16) | (unsigned)src[e];
            atomicAdd(&h[d >> BSH], 1);
            cnt = j + 1;
        }
    }
    __syncthreads();
    for (int i = threadIdx.x; i < nb; i += 256) {
        int c = h[i];
        base[i] = c ? atomicAdd(&bcur[i], c) : 0;
    }
    __syncthreads();
#pragma unroll
    for (int j = 0; j < BIN_EPT; j++) {
        if (j < cnt) {
            int pos = atomicAdd(&base[u[j] >> 22], 1);
            pairs[pos] = u[j];
        }
    }
}

// ---------------- per-bucket: deg, row_ptr, dinv, CSR col fill ----------
__global__ __launch_bounds__(256) void k_fill2(const unsigned* __restrict__ pairs,
                                               const int* __restrict__ bptr,
                                               int* __restrict__ row_ptr,
                                               float* __restrict__ dinv,
                                               int* __restrict__ col,
                                               int N, int nb, int E) {
    __shared__ int ldeg[64];
    __shared__ int lcur[64];
    int b = blockIdx.x;
    int node0 = b << BSH;
    int beg = bptr[b], end = bptr[b + 1];
    if (threadIdx.x < 64) ldeg[threadIdx.x] = 0;
    __syncthreads();
    for (int i = beg + threadIdx.x; i < end; i += 256)
        atomicAdd(&ldeg[(pairs[i] >> 16) & 63], 1);
    __syncthreads();
    if (threadIdx.x < 64) {  // wave 0: scan 64 degrees
        int d = ldeg[threadIdx.x];
        int x = d;
#pragma unroll
        for (int off = 1; off < 64; off <<= 1) {
            int y = __shfl_up(x, off, 64);
            if ((int)threadIdx.x >= off) x += y;
        }
        int node = node0 + threadIdx.x;
        if (node < N) {
            int rp = beg + (x - d);
            row_ptr[node] = rp;
            lcur[threadIdx.x] = rp;
            dinv[node] = rsqrtf((float)d + 1.0f);
        }
        if (b == nb - 1 && threadIdx.x == 0) row_ptr[N] = E;
    }
    __syncthreads();
    for (int i = beg + threadIdx.x; i < end; i += 256) {
        unsigned u = pairs[i];
        int pos = atomicAdd(&lcur[(u >> 16) & 63], 1);
        col[pos] = (int)(u & 0xffffu);
    }
}

// ---------------- GEMM: H' = dinv * (X @ W), fp16 out -------------------
#define GR 64
#define SXS 132   // padded X row stride (floats)
#define KB 32     // K-quarter

__global__ __launch_bounds__(256) void k_gemm(const float* __restrict__ X,
                                              const float* __restrict__ W,
                                              const float* __restrict__ dinv,
                                              __half2* __restrict__ Hh, int N) {
    __shared__ float sW[KB * 128];    // 16KB
    __shared__ float sX[GR * SXS];    // 33.8KB
    int t = threadIdx.x;
    int row0 = blockIdx.x * GR;
    int nrow = N - row0; if (nrow > GR) nrow = GR;

    {   // stage X tile once
        const float4* X4 = (const float4*)(X + (size_t)row0 * DIM);
        float4* sX4 = (float4*)sX;
        for (int idx = t; idx < nrow * 32; idx += 256) {
            int r = idx >> 5, c = idx & 31;
            sX4[r * (SXS / 4) + c] = X4[idx];
        }
    }

    int cg = t & 31;   // cols cg*4 .. cg*4+3
    int rg = t >> 5;   // rows rg*8 .. rg*8+7
    float acc[8][4];
#pragma unroll
    for (int r = 0; r < 8; r++)
#pragma unroll
        for (int c = 0; c < 4; c++) acc[r][c] = 0.f;

    const float* sWp = sW + cg * 4;
    const float* sXbase = sX + (rg * 8) * SXS;

#define FMA4(xs, wv)                                  \
    acc[r][0] = fmaf((xs), (wv).x, acc[r][0]);        \
    acc[r][1] = fmaf((xs), (wv).y, acc[r][1]);        \
    acc[r][2] = fmaf((xs), (wv).z, acc[r][2]);        \
    acc[r][3] = fmaf((xs), (wv).w, acc[r][3]);

    for (int kb = 0; kb < 128; kb += KB) {
        __syncthreads();
        {   // stage W rows kb..kb+KB-1
            const float4* W4 = (const float4*)(W + (size_t)kb * 128);
            float4* sW4 = (float4*)sW;
#pragma unroll
            for (int i = 0; i < (KB * 32) / 256; i++) sW4[t + i * 256] = W4[t + i * 256];
        }
        __syncthreads();
        const float* sXp = sXbase + kb;
        for (int k = 0; k < KB; k += 4) {
            float4 wv0 = *(const float4*)(sWp + (k + 0) * 128);
            float4 wv1 = *(const float4*)(sWp + (k + 1) * 128);
            float4 wv2 = *(const float4*)(sWp + (k + 2) * 128);
            float4 wv3 = *(const float4*)(sWp + (k + 3) * 128);
#pragma unroll
            for (int r = 0; r < 8; r++) {
                float4 xv = *(const float4*)(sXp + r * SXS + k);
                FMA4(xv.x, wv0)
                FMA4(xv.y, wv1)
                FMA4(xv.z, wv2)
                FMA4(xv.w, wv3)
            }
        }
    }
#undef FMA4

#pragma unroll
    for (int r = 0; r < 8; r++) {
        int rr = rg * 8 + r;
        if (rr < nrow) {
            float di = dinv[row0 + rr];
            union { __half2 h[2]; uint2 u; } pk;
            pk.h[0] = __floats2half2_rn(acc[r][0] * di, acc[r][1] * di);
            pk.h[1] = __floats2half2_rn(acc[r][2] * di, acc[r][3] * di);
            *(uint2*)(Hh + (size_t)(row0 + rr) * 64 + cg * 2) = pk.u;
        }
    }
}

// ---------------- aggregation core: one wave per dst node ----------------
__device__ __forceinline__ float2 agg_row(const __half2* __restrict__ Hh,
                                          const int* __restrict__ row_ptr,
                                          const int* __restrict__ col,
                                          const float* __restrict__ dinv,
                                          const float* __restrict__ B,
                                          int wid, int lane) {
    int beg = __builtin_amdgcn_readfirstlane(row_ptr[wid]);
    int end = __builtin_amdgcn_readfirstlane(row_ptr[wid + 1]);
    const __half2* Hl = Hh + lane;  // row s -> Hl[s*64]
    float2 s0f = __half22float2(Hl[(size_t)wid * 64]);  // self (H'[d])
    float ax = s0f.x, ay = s0f.y;
    float bx = 0.f, by = 0.f, cx = 0.f, cy = 0.f, dx = 0.f, dy = 0.f;

    int e = beg;
    for (; e + 8 <= end; e += 8) {
        int s0 = col[e + 0], s1 = col[e + 1], s2 = col[e + 2], s3 = col[e + 3];
        int s4 = col[e + 4], s5 = col[e + 5], s6 = col[e + 6], s7 = col[e + 7];
        __half2 g0 = Hl[(size_t)s0 * 64];
        __half2 g1 = Hl[(size_t)s1 * 64];
        __half2 g2 = Hl[(size_t)s2 * 64];
        __half2 g3 = Hl[(size_t)s3 * 64];
        __half2 g4 = Hl[(size_t)s4 * 64];
        __half2 g5 = Hl[(size_t)s5 * 64];
        __half2 g6 = Hl[(size_t)s6 * 64];
        __half2 g7 = Hl[(size_t)s7 * 64];
        float2 f0 = __half22float2(g0), f1 = __half22float2(g1);
        float2 f2 = __half22float2(g2), f3 = __half22float2(g3);
        float2 f4 = __half22float2(g4), f5 = __half22float2(g5);
        float2 f6 = __half22float2(g6), f7 = __half22float2(g7);
        ax += f0.x; ay += f0.y;  bx += f1.x; by += f1.y;
        cx += f2.x; cy += f2.y;  dx += f3.x; dy += f3.y;
        ax += f4.x; ay += f4.y;  bx += f5.x; by += f5.y;
        cx += f6.x; cy += f6.y;  dx += f7.x; dy += f7.y;
    }
    for (; e + 4 <= end; e += 4) {
        int s0 = col[e + 0], s1 = col[e + 1], s2 = col[e + 2], s3 = col[e + 3];
        __half2 g0 = Hl[(size_t)s0 * 64];
        __half2 g1 = Hl[(size_t)s1 * 64];
        __half2 g2 = Hl[(size_t)s2 * 64];
        __half2 g3 = Hl[(size_t)s3 * 64];
        float2 f0 = __half22float2(g0), f1 = __half22float2(g1);
        float2 f2 = __half22float2(g2), f3 = __half22float2(g3);
        ax += f0.x; ay += f0.y;  bx += f1.x; by += f1.y;
        cx += f2.x; cy += f2.y;  dx += f3.x; dy += f3.y;
    }
    for (; e < end; e++) {
        float2 f = __half22float2(Hl[(size_t)col[e] * 64]);
        ax += f.x; ay += f.y;
    }
    ax += bx + cx + dx;
    ay += by + cy + dy;

    float di = dinv[wid];
    float2 b = *(const float2*)(B + lane * 2);
    return make_float2(fmaf(di, ax, b.x), fmaf(di, ay, b.y));
}

// layer-1: write relu'd fp32 row
__global__ __launch_bounds__(256) void k_agg(const __half2* __restrict__ Hh,
                                             const int* __restrict__ row_ptr,
                                             const int* __restrict__ col,
                                             const float* __restrict__ dinv,
                                             const float* __restrict__ B,
                                             float* __restrict__ O, int N) {
    int wid = (blockIdx.x * 256 + threadIdx.x) >> 6;
    int lane = threadIdx.x & 63;
    if (wid >= N) return;
    float2 r = agg_row(Hh, row_ptr, col, dinv, B, wid, lane);
    r.x = fmaxf(r.x, 0.f);
    r.y = fmaxf(r.y, 0.f);
    *(float2*)(O + (size_t)wid * DIM + lane * 2) = r;
}

// layer-2 + readout fused: out[n] = dot(relu(row), Wr) + br
__global__ __launch_bounds__(256) void k_agg_out(const __half2* __restrict__ Hh,
                                                 const int* __restrict__ row_ptr,
                                                 const int* __restrict__ col,
                                                 const float* __restrict__ dinv,
                                                 const float* __restrict__ B,
                                                 const float* __restrict__ Wr,
                                                 const float* __restrict__ br,
                                                 float* __restrict__ out, int N) {
    int wid = (blockIdx.x * 256 + threadIdx.x) >> 6;
    int lane = threadIdx.x & 63;
    if (wid >= N) return;
    float2 r = agg_row(Hh, row_ptr, col, dinv, B, wid, lane);
    float2 w = *(const float2*)(Wr + lane * 2);
    float v = fmaxf(r.x, 0.f) * w.x + fmaxf(r.y, 0.f) * w.y;
#pragma unroll
    for (int off = 32; off > 0; off >>= 1) v += __shfl_down(v, off, 64);
    if (lane == 0) out[wid] = v + br[0];
}

extern "C" void kernel_launch(void* const* d_in, const int* in_sizes, int n_in,
                              void* d_out, int out_size, void* d_ws, size_t ws_size,
                              hipStream_t stream) {
    const float* x  = (const float*)d_in[0];
    const int*   ei = (const int*)d_in[1];
    const float* W1 = (const float*)d_in[2];
    const float* b1 = (const float*)d_in[3];
    const float* W2 = (const float*)d_in[4];
    const float* b2 = (const float*)d_in[5];
    const float* Wr = (const float*)d_in[6];
    const float* br = (const float*)d_in[7];

    const int N = in_sizes[0] / DIM;
    const int E = in_sizes[1] / 2;
    const int* src = ei;
    const int* dst = ei + E;
    const int NB = (N + 63) >> BSH;  // buckets of 64 nodes

    char* p = (char*)d_ws;
    auto alloc = [&](size_t bytes) -> void* {
        void* r = (void*)p;
        p += (bytes + 255) & ~(size_t)255;
        return r;
    };
    __half2*  Hh      = (__half2*)alloc((size_t)N * DIM * 2);  // fp16 H'
    float*    A1      = (float*)alloc((size_t)N * DIM * 4);    // layer-1 out fp32
    float*    dinv    = (float*)alloc((size_t)N * 4);
    int*      row_ptr = (int*)alloc((size_t)(N + 1) * 4);
    int*      bcount  = (int*)alloc((size_t)NB * 4);
    int*      bptr    = (int*)alloc((size_t)(NB + 1) * 4);
    int*      bcur    = (int*)alloc((size_t)NB * 4);
    unsigned* pairs   = (unsigned*)alloc((size_t)E * 4);
    int*      col     = (int*)alloc((size_t)E * 4);
    (void)ws_size; (void)n_in;

    hipMemsetAsync(bcount, 0, (size_t)NB * 4, stream);

    k_hist<<<256, 256, 0, stream>>>(dst, bcount, E, NB);
    k_bscan<<<1, 1024, 0, stream>>>(bcount, bptr, bcur, NB, E);
    const int binb = (E + 256 * BIN_EPT - 1) / (256 * BIN_EPT);
    k_bin<<<binb, 256, 0, stream>>>(src, dst, bcur, pairs, E, NB);
    k_fill2<<<NB, 256, 0, stream>>>(pairs, bptr, row_ptr, dinv, col, N, NB, E);

    const int gb = (N + GR - 1) / GR;
    const int ab = (N * 64 + 255) / 256;

    k_gemm<<<gb, 256, 0, stream>>>(x, W1, dinv, Hh, N);
    k_agg<<<ab, 256, 0, stream>>>(Hh, row_ptr, col, dinv, b1, A1, N);
    k_gemm<<<gb, 256, 0, stream>>>(A1, W2, dinv, Hh, N);
    k_agg_out<<<ab, 256, 0, stream>>>(Hh, row_ptr, col, dinv, b2, Wr, br,
                                      (float*)d_out, N);
}

// Round 6
// 143.952 us; speedup vs baseline: 2.6387x; 1.2142x over previous
//
#include <hip/hip_runtime.h>
#include <hip/hip_fp16.h>
#include <cstdint>
#include <cstddef>

// GCN refold: H'_l = dinv * (X_l @ W_l)  (fp16, row-major half-packed)
//   layer out[d] = relu( dinv[d] * (sum_e H'[src_e] + H'[d]) + b )
// GEMM via MFMA bf16 hi/lo split (Xh·Wh + Xl·Wh + Xh·Wl), fp32 accum.
// CSR build via 64-node buckets (all scatter LDS-local).
// Requires N < 65536 (pairs pack (dst<<16)|src). N = 50000 here.

constexpr int DIM = 128;
#define BSH 6                 // 64 nodes per bucket
#define BIN_EPT 13            // edges per thread in k_bin

typedef __attribute__((ext_vector_type(8))) short bf16x8;   // 8 bf16 (4 VGPRs)
typedef __attribute__((ext_vector_type(4))) float f32x4;

__device__ __forceinline__ short bf16h(float x) {
    unsigned u = __float_as_uint(x);
    return (short)((u + 0x7FFFu + ((u >> 16) & 1u)) >> 16);  // RNE bf16
}
__device__ __forceinline__ float bf16f(short h) {
    return __uint_as_float(((unsigned)(unsigned short)h) << 16);
}

// ---------------- bucket histogram (LDS-privatized) ----------------
__global__ __launch_bounds__(256) void k_hist(const int* __restrict__ dst,
                                              int* __restrict__ bcount, int E, int nb) {
    __shared__ int h[1024];
    for (int i = threadIdx.x; i < nb; i += 256) h[i] = 0;
    __syncthreads();
    int stride = gridDim.x * 256;
    for (int e = blockIdx.x * 256 + threadIdx.x; e < E; e += stride)
        atomicAdd(&h[dst[e] >> BSH], 1);
    __syncthreads();
    for (int i = threadIdx.x; i < nb; i += 256) {
        int c = h[i];
        if (c) atomicAdd(&bcount[i], c);
    }
}

// ---------------- bucket exclusive scan (single block) ----------------
__global__ __launch_bounds__(1024) void k_bscan(const int* __restrict__ bcount,
                                                int* __restrict__ bptr,
                                                int* __restrict__ bcur, int nb, int E) {
    __shared__ int s[1024];
    int t = threadIdx.x;
    int v = (t < nb) ? bcount[t] : 0;
    s[t] = v;
    __syncthreads();
    for (int off = 1; off < 1024; off <<= 1) {
        int u = (t >= off) ? s[t - off] : 0;
        __syncthreads();
        s[t] += u;
        __syncthreads();
    }
    if (t < nb) { int ex = s[t] - v; bptr[t] = ex; bcur[t] = ex; }
    if (t == 0) bptr[nb] = E;
}

// ---------------- bin edges into bucket runs (block-level reservation) ----
__global__ __launch_bounds__(256) void k_bin(const int* __restrict__ src,
                                             const int* __restrict__ dst,
                                             int* __restrict__ bcur,
                                             unsigned* __restrict__ pairs,
                                             int E, int nb) {
    __shared__ int h[1024];     // local counts
    __shared__ int base[1024];  // reserved cursors
    for (int i = threadIdx.x; i < nb; i += 256) h[i] = 0;
    __syncthreads();

    int e0 = blockIdx.x * 256 * BIN_EPT;
    unsigned u[BIN_EPT];
    int cnt = 0;
#pragma unroll
    for (int j = 0; j < BIN_EPT; j++) {
        int e = e0 + j * 256 + threadIdx.x;
        if (e < E) {
            int d = dst[e];
            u[j] = ((unsigned)d << 16) | (unsigned)src[e];
            atomicAdd(&h[d >> BSH], 1);
            cnt = j + 1;
        }
    }
    __syncthreads();
    for (int i = threadIdx.x; i < nb; i += 256) {
        int c = h[i];
        base[i] = c ? atomicAdd(&bcur[i], c) : 0;
    }
    __syncthreads();
#pragma unroll
    for (int j = 0; j < BIN_EPT; j++) {
        if (j < cnt) {
            int pos = atomicAdd(&base[u[j] >> 22], 1);
            pairs[pos] = u[j];
        }
    }
}

// ---------------- per-bucket: deg, row_ptr, dinv, CSR col fill ----------
__global__ __launch_bounds__(256) void k_fill2(const unsigned* __restrict__ pairs,
                                               const int* __restrict__ bptr,
                                               int* __restrict__ row_ptr,
                                               float* __restrict__ dinv,
                                               int* __restrict__ col,
                                               int N, int nb, int E) {
    __shared__ int ldeg[64];
    __shared__ int lcur[64];
    int b = blockIdx.x;
    int node0 = b << BSH;
    int beg = bptr[b], end = bptr[b + 1];
    if (threadIdx.x < 64) ldeg[threadIdx.x] = 0;
    __syncthreads();
    for (int i = beg + threadIdx.x; i < end; i += 256)
        atomicAdd(&ldeg[(pairs[i] >> 16) & 63], 1);
    __syncthreads();
    if (threadIdx.x < 64) {  // wave 0: scan 64 degrees
        int d = ldeg[threadIdx.x];
        int x = d;
#pragma unroll
        for (int off = 1; off < 64; off <<= 1) {
            int y = __shfl_up(x, off, 64);
            if ((int)threadIdx.x >= off) x += y;
        }
        int node = node0 + threadIdx.x;
        if (node < N) {
            int rp = beg + (x - d);
            row_ptr[node] = rp;
            lcur[threadIdx.x] = rp;
            dinv[node] = rsqrtf((float)d + 1.0f);
        }
        if (b == nb - 1 && threadIdx.x == 0) row_ptr[N] = E;
    }
    __syncthreads();
    for (int i = beg + threadIdx.x; i < end; i += 256) {
        unsigned u = pairs[i];
        int pos = atomicAdd(&lcur[(u >> 16) & 63], 1);
        col[pos] = (int)(u & 0xffffu);
    }
}

// ---------------- W -> fragment-ordered bf16 hi/lo ----------------------
// Frag layout (16x16x32 B-operand): idx = ((nt*4+ks)*64 + lane)*8 + j
//   element = W[(ks*32 + (lane>>4)*8 + j)*128 + nt*16 + (lane&15)]
__global__ __launch_bounds__(256) void k_wfrag(const float* __restrict__ W,
                                               short* __restrict__ Bh,
                                               short* __restrict__ Bl) {
    int idx = blockIdx.x * 256 + threadIdx.x;   // 0..16383
    int j  = idx & 7;
    int l  = (idx >> 3) & 63;
    int ks = (idx >> 9) & 3;
    int nt = idx >> 11;
    int k   = ks * 32 + ((l >> 4) * 8) + j;
    int c   = nt * 16 + (l & 15);
    float w = W[k * 128 + c];
    short h = bf16h(w);
    Bh[idx] = h;
    Bl[idx] = bf16h(w - bf16f(h));
}

// ---------------- MFMA GEMM: H' = dinv * (X @ W), fp16 out --------------
// One wave per 16 rows; no LDS, no barriers. 96 MFMA/wave (8 nt x 4 ks x 3).
__global__ __launch_bounds__(256) void k_mm(const float* __restrict__ X,
                                            const short* __restrict__ Bhp,
                                            const short* __restrict__ Blp,
                                            const float* __restrict__ dinv,
                                            __half* __restrict__ Hh, int N) {
    int gw   = (blockIdx.x * 256 + threadIdx.x) >> 6;
    int lane = threadIdx.x & 63;
    int row0 = gw * 16;
    if (row0 >= N) return;

    int arow = row0 + (lane & 15);
    if (arow >= N) arow = N - 1;           // duplicate load; rows >= N not stored
    const float* Xp = X + (size_t)arow * DIM + ((lane >> 4) * 8);

    bf16x8 Ah[4], Al[4];
#pragma unroll
    for (int ks = 0; ks < 4; ks++) {
        float4 a = *(const float4*)(Xp + ks * 32);
        float4 b = *(const float4*)(Xp + ks * 32 + 4);
        float v[8] = {a.x, a.y, a.z, a.w, b.x, b.y, b.z, b.w};
        bf16x8 h, lo;
#pragma unroll
        for (int j = 0; j < 8; j++) {
            short hh = bf16h(v[j]);
            h[j] = hh;
            lo[j] = bf16h(v[j] - bf16f(hh));
        }
        Ah[ks] = h;
        Al[ks] = lo;
    }

    const bf16x8* BH = (const bf16x8*)Bhp;
    const bf16x8* BL = (const bf16x8*)Blp;

    f32x4 acc[8];
#pragma unroll
    for (int nt = 0; nt < 8; nt++) {
        f32x4 c = {0.f, 0.f, 0.f, 0.f};
#pragma unroll
        for (int ks = 0; ks < 4; ks++) {
            bf16x8 bh = BH[(nt * 4 + ks) * 64 + lane];
            bf16x8 bl = BL[(nt * 4 + ks) * 64 + lane];
            c = __builtin_amdgcn_mfma_f32_16x16x32_bf16(Ah[ks], bh, c, 0, 0, 0);
            c = __builtin_amdgcn_mfma_f32_16x16x32_bf16(Al[ks], bh, c, 0, 0, 0);
            c = __builtin_amdgcn_mfma_f32_16x16x32_bf16(Ah[ks], bl, c, 0, 0, 0);
        }
        acc[nt] = c;
    }

    // C/D: col = lane&15 (+nt*16), row = (lane>>4)*4 + reg   [m89/m91]
    int rb = row0 + ((lane >> 4) * 4);
    int cb = lane & 15;
#pragma unroll
    for (int r = 0; r < 4; r++) {
        if (rb + r < N) {
            float dv = dinv[rb + r];
            __half* out = Hh + (size_t)(rb + r) * DIM + cb;
#pragma unroll
            for (int nt = 0; nt < 8; nt++)
                out[nt * 16] = __float2half(acc[nt][r] * dv);
        }
    }
}

// ---------------- aggregation core: one wave per dst node ----------------
__device__ __forceinline__ float2 agg_row(const __half2* __restrict__ Hh,
                                          const int* __restrict__ row_ptr,
                                          const int* __restrict__ col,
                                          const float* __restrict__ dinv,
                                          const float* __restrict__ B,
                                          int wid, int lane) {
    int beg = __builtin_amdgcn_readfirstlane(row_ptr[wid]);
    int end = __builtin_amdgcn_readfirstlane(row_ptr[wid + 1]);
    const __half2* Hl = Hh + lane;  // row s -> Hl[s*64]
    float2 s0f = __half22float2(Hl[(size_t)wid * 64]);  // self (H'[d])
    float ax = s0f.x, ay = s0f.y;
    float bx = 0.f, by = 0.f, cx = 0.f, cy = 0.f, dx = 0.f, dy = 0.f;

    int e = beg;
    for (; e + 8 <= end; e += 8) {
        int s0 = col[e + 0], s1 = col[e + 1], s2 = col[e + 2], s3 = col[e + 3];
        int s4 = col[e + 4], s5 = col[e + 5], s6 = col[e + 6], s7 = col[e + 7];
        __half2 g0 = Hl[(size_t)s0 * 64];
        __half2 g1 = Hl[(size_t)s1 * 64];
        __half2 g2 = Hl[(size_t)s2 * 64];
        __half2 g3 = Hl[(size_t)s3 * 64];
        __half2 g4 = Hl[(size_t)s4 * 64];
        __half2 g5 = Hl[(size_t)s5 * 64];
        __half2 g6 = Hl[(size_t)s6 * 64];
        __half2 g7 = Hl[(size_t)s7 * 64];
        float2 f0 = __half22float2(g0), f1 = __half22float2(g1);
        float2 f2 = __half22float2(g2), f3 = __half22float2(g3);
        float2 f4 = __half22float2(g4), f5 = __half22float2(g5);
        float2 f6 = __half22float2(g6), f7 = __half22float2(g7);
        ax += f0.x; ay += f0.y;  bx += f1.x; by += f1.y;
        cx += f2.x; cy += f2.y;  dx += f3.x; dy += f3.y;
        ax += f4.x; ay += f4.y;  bx += f5.x; by += f5.y;
        cx += f6.x; cy += f6.y;  dx += f7.x; dy += f7.y;
    }
    for (; e + 4 <= end; e += 4) {
        int s0 = col[e + 0], s1 = col[e + 1], s2 = col[e + 2], s3 = col[e + 3];
        __half2 g0 = Hl[(size_t)s0 * 64];
        __half2 g1 = Hl[(size_t)s1 * 64];
        __half2 g2 = Hl[(size_t)s2 * 64];
        __half2 g3 = Hl[(size_t)s3 * 64];
        float2 f0 = __half22float2(g0), f1 = __half22float2(g1);
        float2 f2 = __half22float2(g2), f3 = __half22float2(g3);
        ax += f0.x; ay += f0.y;  bx += f1.x; by += f1.y;
        cx += f2.x; cy += f2.y;  dx += f3.x; dy += f3.y;
    }
    for (; e < end; e++) {
        float2 f = __half22float2(Hl[(size_t)col[e] * 64]);
        ax += f.x; ay += f.y;
    }
    ax += bx + cx + dx;
    ay += by + cy + dy;

    float di = dinv[wid];
    float2 b = *(const float2*)(B + lane * 2);
    return make_float2(fmaf(di, ax, b.x), fmaf(di, ay, b.y));
}

// layer-1: write relu'd fp32 row
__global__ __launch_bounds__(256) void k_agg(const __half2* __restrict__ Hh,
                                             const int* __restrict__ row_ptr,
                                             const int* __restrict__ col,
                                             const float* __restrict__ dinv,
                                             const float* __restrict__ B,
                                             float* __restrict__ O, int N) {
    int wid = (blockIdx.x * 256 + threadIdx.x) >> 6;
    int lane = threadIdx.x & 63;
    if (wid >= N) return;
    float2 r = agg_row(Hh, row_ptr, col, dinv, B, wid, lane);
    r.x = fmaxf(r.x, 0.f);
    r.y = fmaxf(r.y, 0.f);
    *(float2*)(O + (size_t)wid * DIM + lane * 2) = r;
}

// layer-2 + readout fused: out[n] = dot(relu(row), Wr) + br
__global__ __launch_bounds__(256) void k_agg_out(const __half2* __restrict__ Hh,
                                                 const int* __restrict__ row_ptr,
                                                 const int* __restrict__ col,
                                                 const float* __restrict__ dinv,
                                                 const float* __restrict__ B,
                                                 const float* __restrict__ Wr,
                                                 const float* __restrict__ br,
                                                 float* __restrict__ out, int N) {
    int wid = (blockIdx.x * 256 + threadIdx.x) >> 6;
    int lane = threadIdx.x & 63;
    if (wid >= N) return;
    float2 r = agg_row(Hh, row_ptr, col, dinv, B, wid, lane);
    float2 w = *(const float2*)(Wr + lane * 2);
    float v = fmaxf(r.x, 0.f) * w.x + fmaxf(r.y, 0.f) * w.y;
#pragma unroll
    for (int off = 32; off > 0; off >>= 1) v += __shfl_down(v, off, 64);
    if (lane == 0) out[wid] = v + br[0];
}

extern "C" void kernel_launch(void* const* d_in, const int* in_sizes, int n_in,
                              void* d_out, int out_size, void* d_ws, size_t ws_size,
                              hipStream_t stream) {
    const float* x  = (const float*)d_in[0];
    const int*   ei = (const int*)d_in[1];
    const float* W1 = (const float*)d_in[2];
    const float* b1 = (const float*)d_in[3];
    const float* W2 = (const float*)d_in[4];
    const float* b2 = (const float*)d_in[5];
    const float* Wr = (const float*)d_in[6];
    const float* br = (const float*)d_in[7];

    const int N = in_sizes[0] / DIM;
    const int E = in_sizes[1] / 2;
    const int* src = ei;
    const int* dst = ei + E;
    const int NB = (N + 63) >> BSH;  // buckets of 64 nodes

    char* p = (char*)d_ws;
    auto alloc = [&](size_t bytes) -> void* {
        void* r = (void*)p;
        p += (bytes + 255) & ~(size_t)255;
        return r;
    };
    __half*   Hh      = (__half*)alloc((size_t)N * DIM * 2);   // fp16 H'
    float*    A1      = (float*)alloc((size_t)N * DIM * 4);    // layer-1 out fp32
    float*    dinv    = (float*)alloc((size_t)N * 4);
    int*      row_ptr = (int*)alloc((size_t)(N + 1) * 4);
    int*      bcount  = (int*)alloc((size_t)NB * 4);
    int*      bptr    = (int*)alloc((size_t)(NB + 1) * 4);
    int*      bcur    = (int*)alloc((size_t)NB * 4);
    unsigned* pairs   = (unsigned*)alloc((size_t)E * 4);
    int*      col     = (int*)alloc((size_t)E * 4);
    short*    Bh1     = (short*)alloc(16384 * 2);
    short*    Bl1     = (short*)alloc(16384 * 2);
    short*    Bh2     = (short*)alloc(16384 * 2);
    short*    Bl2     = (short*)alloc(16384 * 2);
    (void)ws_size; (void)n_in;

    hipMemsetAsync(bcount, 0, (size_t)NB * 4, stream);

    // CSR build
    k_hist<<<256, 256, 0, stream>>>(dst, bcount, E, NB);
    k_bscan<<<1, 1024, 0, stream>>>(bcount, bptr, bcur, NB, E);
    const int binb = (E + 256 * BIN_EPT - 1) / (256 * BIN_EPT);
    k_bin<<<binb, 256, 0, stream>>>(src, dst, bcur, pairs, E, NB);
    k_fill2<<<NB, 256, 0, stream>>>(pairs, bptr, row_ptr, dinv, col, N, NB, E);

    // W fragment prep (bf16 hi/lo)
    k_wfrag<<<64, 256, 0, stream>>>(W1, Bh1, Bl1);
    k_wfrag<<<64, 256, 0, stream>>>(W2, Bh2, Bl2);

    const int mmb = ((N + 15) / 16 + 3) / 4;   // waves of 16 rows, 4 waves/block
    const int ab  = (N * 64 + 255) / 256;

    k_mm<<<mmb, 256, 0, stream>>>(x, Bh1, Bl1, dinv, Hh, N);
    k_agg<<<ab, 256, 0, stream>>>((const __half2*)Hh, row_ptr, col, dinv, b1, A1, N);
    k_mm<<<mmb, 256, 0, stream>>>(A1, Bh2, Bl2, dinv, Hh, N);
    k_agg_out<<<ab, 256, 0, stream>>>((const __half2*)Hh, row_ptr, col, dinv, b2,
                                      Wr, br, (float*)d_out, N);
}

// Round 7
// 138.836 us; speedup vs baseline: 2.7359x; 1.0369x over previous
//
#include <hip/hip_runtime.h>
#include <hip/hip_fp16.h>
#include <cstdint>
#include <cstddef>

// GCN refold: H'_l = dinv * (X_l @ W_l)  (fp16), layer out = relu(dinv*(sum+self)+b)
// GEMM via MFMA bf16 hi/lo split. CSR build via 64-node buckets; edges within
// each row placed in src-tile order (8 tiles x 8192 nodes) for L2 temporal
// locality during aggregation. Requires N < 65536.

constexpr int DIM = 128;
#define BSH 6                 // 64 nodes per bucket
#define BIN_EPT 13            // edges per thread in k_bin
#define FT 8                  // src tiles
#define FSH 13                // tile = src >> 13 (8192 nodes/tile)
#define STAGE 2048            // LDS edge stage per bucket

typedef __attribute__((ext_vector_type(8))) short bf16x8;   // 8 bf16 (4 VGPRs)
typedef __attribute__((ext_vector_type(4))) float f32x4;

__device__ __forceinline__ short bf16h(float x) {
    unsigned u = __float_as_uint(x);
    return (short)((u + 0x7FFFu + ((u >> 16) & 1u)) >> 16);  // RNE bf16
}
__device__ __forceinline__ float bf16f(short h) {
    return __uint_as_float(((unsigned)(unsigned short)h) << 16);
}

// ---------------- bucket histogram (LDS-privatized) ----------------
__global__ __launch_bounds__(256) void k_hist(const int* __restrict__ dst,
                                              int* __restrict__ bcount, int E, int nb) {
    __shared__ int h[1024];
    for (int i = threadIdx.x; i < nb; i += 256) h[i] = 0;
    __syncthreads();
    int stride = gridDim.x * 256;
    for (int e = blockIdx.x * 256 + threadIdx.x; e < E; e += stride)
        atomicAdd(&h[dst[e] >> BSH], 1);
    __syncthreads();
    for (int i = threadIdx.x; i < nb; i += 256) {
        int c = h[i];
        if (c) atomicAdd(&bcount[i], c);
    }
}

// ---------------- bucket exclusive scan (single block) ----------------
__global__ __launch_bounds__(1024) void k_bscan(const int* __restrict__ bcount,
                                                int* __restrict__ bptr,
                                                int* __restrict__ bcur, int nb, int E) {
    __shared__ int s[1024];
    int t = threadIdx.x;
    int v = (t < nb) ? bcount[t] : 0;
    s[t] = v;
    __syncthreads();
    for (int off = 1; off < 1024; off <<= 1) {
        int u = (t >= off) ? s[t - off] : 0;
        __syncthreads();
        s[t] += u;
        __syncthreads();
    }
    if (t < nb) { int ex = s[t] - v; bptr[t] = ex; bcur[t] = ex; }
    if (t == 0) bptr[nb] = E;
}

// ---------------- bin edges into bucket runs (block-level reservation) ----
__global__ __launch_bounds__(256) void k_bin(const int* __restrict__ src,
                                             const int* __restrict__ dst,
                                             int* __restrict__ bcur,
                                             unsigned* __restrict__ pairs,
                                             int E, int nb) {
    __shared__ int h[1024];     // local counts
    __shared__ int base[1024];  // reserved cursors
    for (int i = threadIdx.x; i < nb; i += 256) h[i] = 0;
    __syncthreads();

    int e0 = blockIdx.x * 256 * BIN_EPT;
    unsigned u[BIN_EPT];
    int cnt = 0;
#pragma unroll
    for (int j = 0; j < BIN_EPT; j++) {
        int e = e0 + j * 256 + threadIdx.x;
        if (e < E) {
            int d = dst[e];
            u[j] = ((unsigned)d << 16) | (unsigned)src[e];
            atomicAdd(&h[d >> BSH], 1);
            cnt = j + 1;
        }
    }
    __syncthreads();
    for (int i = threadIdx.x; i < nb; i += 256) {
        int c = h[i];
        base[i] = c ? atomicAdd(&bcur[i], c) : 0;
    }
    __syncthreads();
#pragma unroll
    for (int j = 0; j < BIN_EPT; j++) {
        if (j < cnt) {
            int pos = atomicAdd(&base[u[j] >> 22], 1);
            pairs[pos] = u[j];
        }
    }
}

// ---- per-bucket: row_ptr, dinv, CSR col fill in src-tile order ----------
__global__ __launch_bounds__(256) void k_fill2(const unsigned* __restrict__ pairs,
                                               const int* __restrict__ bptr,
                                               int* __restrict__ row_ptr,
                                               float* __restrict__ dinv,
                                               int* __restrict__ col,
                                               int N, int nb, int E) {
    __shared__ unsigned sp[STAGE];
    __shared__ int lcnt[64 * FT];   // counts, then running cursors
    int b = blockIdx.x;
    int node0 = b << BSH;
    int beg = bptr[b], end = bptr[b + 1];
    int cnt = end - beg;
    bool useStage = (cnt <= STAGE);

    for (int i = threadIdx.x; i < 64 * FT; i += 256) lcnt[i] = 0;
    __syncthreads();

    // pass A: (stage +) count per (node, src-tile)
    for (int i = threadIdx.x; i < cnt; i += 256) {
        unsigned u = pairs[beg + i];
        if (useStage) sp[i] = u;
        atomicAdd(&lcnt[((u >> 16) & 63) * FT + ((u & 0xffffu) >> FSH)], 1);
    }
    __syncthreads();

    // wave 0: per-node totals, wave-scan, write row_ptr/dinv, tile cursors
    if (threadIdx.x < 64) {
        int t = threadIdx.x;
        int c[FT]; int sum = 0;
#pragma unroll
        for (int f = 0; f < FT; f++) { c[f] = lcnt[t * FT + f]; sum += c[f]; }
        int x = sum;
#pragma unroll
        for (int off = 1; off < 64; off <<= 1) {
            int y = __shfl_up(x, off, 64);
            if (t >= off) x += y;
        }
        int nodebase = beg + x - sum;   // exclusive in-bucket prefix
        int node = node0 + t;
        if (node < N) {
            row_ptr[node] = nodebase;
            dinv[node] = rsqrtf((float)sum + 1.0f);
        }
        int run = nodebase;
#pragma unroll
        for (int f = 0; f < FT; f++) { lcnt[t * FT + f] = run; run += c[f]; }
        if (b == nb - 1 && t == 0) row_ptr[N] = E;
    }
    __syncthreads();

    // pass B: place
    for (int i = threadIdx.x; i < cnt; i += 256) {
        unsigned u = useStage ? sp[i] : pairs[beg + i];
        unsigned s = u & 0xffffu;
        int pos = atomicAdd(&lcnt[((u >> 16) & 63) * FT + (s >> FSH)], 1);
        col[pos] = (int)s;
    }
}

// ---------------- W -> fragment-ordered bf16 hi/lo (both layers) --------
// Frag layout (16x16x32 B-operand): idx = ((nt*4+ks)*64 + lane)*8 + j
//   element = W[(ks*32 + (lane>>4)*8 + j)*128 + nt*16 + (lane&15)]
// Also zero-inits bcount (runs before k_hist on the same stream).
__global__ __launch_bounds__(256) void k_wfrag2(const float* __restrict__ W1,
                                                const float* __restrict__ W2,
                                                short* __restrict__ Bh1,
                                                short* __restrict__ Bl1,
                                                short* __restrict__ Bh2,
                                                short* __restrict__ Bl2,
                                                int* __restrict__ bcount, int nb) {
    int idx = blockIdx.x * 256 + threadIdx.x;   // 0..32767
    if (idx < nb) bcount[idx] = 0;
    const float* W = (idx < 16384) ? W1 : W2;
    short* Bh = (idx < 16384) ? Bh1 : Bh2;
    short* Bl = (idx < 16384) ? Bl1 : Bl2;
    int id = idx & 16383;
    int j  = id & 7;
    int l  = (id >> 3) & 63;
    int ks = (id >> 9) & 3;
    int nt = id >> 11;
    int k   = ks * 32 + ((l >> 4) * 8) + j;
    int c   = nt * 16 + (l & 15);
    float w = W[k * 128 + c];
    short h = bf16h(w);
    Bh[id] = h;
    Bl[id] = bf16h(w - bf16f(h));
}

// ---------------- MFMA GEMM: H' = dinv * (X @ W), fp16 out --------------
__device__ __forceinline__ void load8(const float* p, float* v) {
    float4 a = *(const float4*)p;
    float4 b = *(const float4*)(p + 4);
    v[0] = a.x; v[1] = a.y; v[2] = a.z; v[3] = a.w;
    v[4] = b.x; v[5] = b.y; v[6] = b.z; v[7] = b.w;
}
__device__ __forceinline__ void load8(const __half* p, float* v) {
    float4 a = *(const float4*)p;   // 8 halves
    const __half2* h = (const __half2*)&a;
#pragma unroll
    for (int i = 0; i < 4; i++) {
        float2 f = __half22float2(h[i]);
        v[2 * i] = f.x; v[2 * i + 1] = f.y;
    }
}

// One wave per 16 rows; no LDS, no barriers. 96 MFMA/wave (8 nt x 4 ks x 3).
template <typename T>
__global__ __launch_bounds__(256) void k_mm(const T* __restrict__ X,
                                            const short* __restrict__ Bhp,
                                            const short* __restrict__ Blp,
                                            const float* __restrict__ dinv,
                                            __half* __restrict__ Hh, int N) {
    int gw   = (blockIdx.x * 256 + threadIdx.x) >> 6;
    int lane = threadIdx.x & 63;
    int row0 = gw * 16;
    if (row0 >= N) return;

    int arow = row0 + (lane & 15);
    if (arow >= N) arow = N - 1;           // duplicate load; rows >= N not stored
    const T* Xp = X + (size_t)arow * DIM + ((lane >> 4) * 8);

    bf16x8 Ah[4], Al[4];
#pragma unroll
    for (int ks = 0; ks < 4; ks++) {
        float v[8];
        load8(Xp + ks * 32, v);
        bf16x8 h, lo;
#pragma unroll
        for (int j = 0; j < 8; j++) {
            short hh = bf16h(v[j]);
            h[j] = hh;
            lo[j] = bf16h(v[j] - bf16f(hh));
        }
        Ah[ks] = h;
        Al[ks] = lo;
    }

    const bf16x8* BH = (const bf16x8*)Bhp;
    const bf16x8* BL = (const bf16x8*)Blp;

    f32x4 acc[8];
#pragma unroll
    for (int nt = 0; nt < 8; nt++) {
        f32x4 c = {0.f, 0.f, 0.f, 0.f};
#pragma unroll
        for (int ks = 0; ks < 4; ks++) {
            bf16x8 bh = BH[(nt * 4 + ks) * 64 + lane];
            bf16x8 bl = BL[(nt * 4 + ks) * 64 + lane];
            c = __builtin_amdgcn_mfma_f32_16x16x32_bf16(Ah[ks], bh, c, 0, 0, 0);
            c = __builtin_amdgcn_mfma_f32_16x16x32_bf16(Al[ks], bh, c, 0, 0, 0);
            c = __builtin_amdgcn_mfma_f32_16x16x32_bf16(Ah[ks], bl, c, 0, 0, 0);
        }
        acc[nt] = c;
    }

    // C/D: col = lane&15 (+nt*16), row = (lane>>4)*4 + reg   [m89/m91]
    int rb = row0 + ((lane >> 4) * 4);
    int cb = lane & 15;
#pragma unroll
    for (int r = 0; r < 4; r++) {
        if (rb + r < N) {
            float dv = dinv[rb + r];
            __half* out = Hh + (size_t)(rb + r) * DIM + cb;
#pragma unroll
            for (int nt = 0; nt < 8; nt++)
                out[nt * 16] = __float2half(acc[nt][r] * dv);
        }
    }
}

// ---------------- aggregation core: one wave per dst node ----------------
__device__ __forceinline__ float2 agg_row(const __half2* __restrict__ Hh,
                                          const int* __restrict__ row_ptr,
                                          const int* __restrict__ col,
                                          const float* __restrict__ dinv,
                                          const float* __restrict__ B,
                                          int wid, int lane) {
    int beg = __builtin_amdgcn_readfirstlane(row_ptr[wid]);
    int end = __builtin_amdgcn_readfirstlane(row_ptr[wid + 1]);
    const __half2* Hl = Hh + lane;  // row s -> Hl[s*64]
    float2 s0f = __half22float2(Hl[(size_t)wid * 64]);  // self (H'[d])
    float ax = s0f.x, ay = s0f.y;
    float bx = 0.f, by = 0.f, cx = 0.f, cy = 0.f, dx = 0.f, dy = 0.f;

    int e = beg;
    for (; e + 8 <= end; e += 8) {
        int s0 = col[e + 0], s1 = col[e + 1], s2 = col[e + 2], s3 = col[e + 3];
        int s4 = col[e + 4], s5 = col[e + 5], s6 = col[e + 6], s7 = col[e + 7];
        __half2 g0 = Hl[(size_t)s0 * 64];
        __half2 g1 = Hl[(size_t)s1 * 64];
        __half2 g2 = Hl[(size_t)s2 * 64];
        __half2 g3 = Hl[(size_t)s3 * 64];
        __half2 g4 = Hl[(size_t)s4 * 64];
        __half2 g5 = Hl[(size_t)s5 * 64];
        __half2 g6 = Hl[(size_t)s6 * 64];
        __half2 g7 = Hl[(size_t)s7 * 64];
        float2 f0 = __half22float2(g0), f1 = __half22float2(g1);
        float2 f2 = __half22float2(g2), f3 = __half22float2(g3);
        float2 f4 = __half22float2(g4), f5 = __half22float2(g5);
        float2 f6 = __half22float2(g6), f7 = __half22float2(g7);
        ax += f0.x; ay += f0.y;  bx += f1.x; by += f1.y;
        cx += f2.x; cy += f2.y;  dx += f3.x; dy += f3.y;
        ax += f4.x; ay += f4.y;  bx += f5.x; by += f5.y;
        cx += f6.x; cy += f6.y;  dx += f7.x; dy += f7.y;
    }
    for (; e + 4 <= end; e += 4) {
        int s0 = col[e + 0], s1 = col[e + 1], s2 = col[e + 2], s3 = col[e + 3];
        __half2 g0 = Hl[(size_t)s0 * 64];
        __half2 g1 = Hl[(size_t)s1 * 64];
        __half2 g2 = Hl[(size_t)s2 * 64];
        __half2 g3 = Hl[(size_t)s3 * 64];
        float2 f0 = __half22float2(g0), f1 = __half22float2(g1);
        float2 f2 = __half22float2(g2), f3 = __half22float2(g3);
        ax += f0.x; ay += f0.y;  bx += f1.x; by += f1.y;
        cx += f2.x; cy += f2.y;  dx += f3.x; dy += f3.y;
    }
    for (; e < end; e++) {
        float2 f = __half22float2(Hl[(size_t)col[e] * 64]);
        ax += f.x; ay += f.y;
    }
    ax += bx + cx + dx;
    ay += by + cy + dy;

    float di = dinv[wid];
    float2 b = *(const float2*)(B + lane * 2);
    return make_float2(fmaf(di, ax, b.x), fmaf(di, ay, b.y));
}

// layer-1: write relu'd fp16 row
__global__ __launch_bounds__(256) void k_agg(const __half2* __restrict__ Hh,
                                             const int* __restrict__ row_ptr,
                                             const int* __restrict__ col,
                                             const float* __restrict__ dinv,
                                             const float* __restrict__ B,
                                             __half2* __restrict__ O, int N) {
    int wid = (blockIdx.x * 256 + threadIdx.x) >> 6;
    int lane = threadIdx.x & 63;
    if (wid >= N) return;
    float2 r = agg_row(Hh, row_ptr, col, dinv, B, wid, lane);
    O[(size_t)wid * 64 + lane] = __floats2half2_rn(fmaxf(r.x, 0.f), fmaxf(r.y, 0.f));
}

// layer-2 + readout fused: out[n] = dot(relu(row), Wr) + br
__global__ __launch_bounds__(256) void k_agg_out(const __half2* __restrict__ Hh,
                                                 const int* __restrict__ row_ptr,
                                                 const int* __restrict__ col,
                                                 const float* __restrict__ dinv,
                                                 const float* __restrict__ B,
                                                 const float* __restrict__ Wr,
                                                 const float* __restrict__ br,
                                                 float* __restrict__ out, int N) {
    int wid = (blockIdx.x * 256 + threadIdx.x) >> 6;
    int lane = threadIdx.x & 63;
    if (wid >= N) return;
    float2 r = agg_row(Hh, row_ptr, col, dinv, B, wid, lane);
    float2 w = *(const float2*)(Wr + lane * 2);
    float v = fmaxf(r.x, 0.f) * w.x + fmaxf(r.y, 0.f) * w.y;
#pragma unroll
    for (int off = 32; off > 0; off >>= 1) v += __shfl_down(v, off, 64);
    if (lane == 0) out[wid] = v + br[0];
}

extern "C" void kernel_launch(void* const* d_in, const int* in_sizes, int n_in,
                              void* d_out, int out_size, void* d_ws, size_t ws_size,
                              hipStream_t stream) {
    const float* x  = (const float*)d_in[0];
    const int*   ei = (const int*)d_in[1];
    const float* W1 = (const float*)d_in[2];
    const float* b1 = (const float*)d_in[3];
    const float* W2 = (const float*)d_in[4];
    const float* b2 = (const float*)d_in[5];
    const float* Wr = (const float*)d_in[6];
    const float* br = (const float*)d_in[7];

    const int N = in_sizes[0] / DIM;
    const int E = in_sizes[1] / 2;
    const int* src = ei;
    const int* dst = ei + E;
    const int NB = (N + 63) >> BSH;  // buckets of 64 nodes

    char* p = (char*)d_ws;
    auto alloc = [&](size_t bytes) -> void* {
        void* r = (void*)p;
        p += (bytes + 255) & ~(size_t)255;
        return r;
    };
    __half*   Hh      = (__half*)alloc((size_t)N * DIM * 2);   // fp16 H'
    __half*   A1      = (__half*)alloc((size_t)N * DIM * 2);   // layer-1 out fp16
    float*    dinv    = (float*)alloc((size_t)N * 4);
    int*      row_ptr = (int*)alloc((size_t)(N + 1) * 4);
    int*      bcount  = (int*)alloc((size_t)NB * 4);
    int*      bptr    = (int*)alloc((size_t)(NB + 1) * 4);
    int*      bcur    = (int*)alloc((size_t)NB * 4);
    unsigned* pairs   = (unsigned*)alloc((size_t)E * 4);
    int*      col     = (int*)alloc((size_t)E * 4);
    short*    Bh1     = (short*)alloc(16384 * 2);
    short*    Bl1     = (short*)alloc(16384 * 2);
    short*    Bh2     = (short*)alloc(16384 * 2);
    short*    Bl2     = (short*)alloc(16384 * 2);
    (void)ws_size; (void)n_in;

    // W frag prep + bcount zero-init (must precede k_hist; same stream)
    k_wfrag2<<<128, 256, 0, stream>>>(W1, W2, Bh1, Bl1, Bh2, Bl2, bcount, NB);

    // CSR build
    k_hist<<<256, 256, 0, stream>>>(dst, bcount, E, NB);
    k_bscan<<<1, 1024, 0, stream>>>(bcount, bptr, bcur, NB, E);
    const int binb = (E + 256 * BIN_EPT - 1) / (256 * BIN_EPT);
    k_bin<<<binb, 256, 0, stream>>>(src, dst, bcur, pairs, E, NB);
    k_fill2<<<NB, 256, 0, stream>>>(pairs, bptr, row_ptr, dinv, col, N, NB, E);

    const int mmb = ((N + 15) / 16 + 3) / 4;   // waves of 16 rows, 4 waves/block
    const int ab  = (N * 64 + 255) / 256;

    k_mm<float><<<mmb, 256, 0, stream>>>(x, Bh1, Bl1, dinv, Hh, N);
    k_agg<<<ab, 256, 0, stream>>>((const __half2*)Hh, row_ptr, col, dinv, b1,
                                  (__half2*)A1, N);
    k_mm<__half><<<mmb, 256, 0, stream>>>(A1, Bh2, Bl2, dinv, Hh, N);
    k_agg_out<<<ab, 256, 0, stream>>>((const __half2*)Hh, row_ptr, col, dinv, b2,
                                      Wr, br, (float*)d_out, N);
}

// Round 8
// 137.563 us; speedup vs baseline: 2.7612x; 1.0093x over previous
//
#include <hip/hip_runtime.h>
#include <hip/hip_fp16.h>
#include <cstdint>
#include <cstddef>

// GCN refold: H'_l = dinv * (X_l @ W_l)  (fp16), layer out = relu(dinv*(sum+self)+b)
// GEMM via MFMA bf16 hi/lo split. CSR build via 64-node buckets.
// Aggregation: one wave per dst row, 16-deep gather batches for MLP.
// Requires N < 65536.

constexpr int DIM = 128;
#define BSH 6                 // 64 nodes per bucket
#define BIN_EPT 13            // edges per thread in k_bin
#define FT 8                  // src tiles (CSR in-row order; harmless)
#define FSH 13
#define STAGE 2048            // LDS edge stage per bucket

typedef __attribute__((ext_vector_type(8))) short bf16x8;   // 8 bf16 (4 VGPRs)
typedef __attribute__((ext_vector_type(4))) float f32x4;

__device__ __forceinline__ short bf16h(float x) {
    unsigned u = __float_as_uint(x);
    return (short)((u + 0x7FFFu + ((u >> 16) & 1u)) >> 16);  // RNE bf16
}
__device__ __forceinline__ float bf16f(short h) {
    return __uint_as_float(((unsigned)(unsigned short)h) << 16);
}

// ---------------- bucket histogram (LDS-privatized) ----------------
__global__ __launch_bounds__(256) void k_hist(const int* __restrict__ dst,
                                              int* __restrict__ bcount, int E, int nb) {
    __shared__ int h[1024];
    for (int i = threadIdx.x; i < nb; i += 256) h[i] = 0;
    __syncthreads();
    int stride = gridDim.x * 256;
    for (int e = blockIdx.x * 256 + threadIdx.x; e < E; e += stride)
        atomicAdd(&h[dst[e] >> BSH], 1);
    __syncthreads();
    for (int i = threadIdx.x; i < nb; i += 256) {
        int c = h[i];
        if (c) atomicAdd(&bcount[i], c);
    }
}

// ---------------- bucket exclusive scan (single block) ----------------
__global__ __launch_bounds__(1024) void k_bscan(const int* __restrict__ bcount,
                                                int* __restrict__ bptr,
                                                int* __restrict__ bcur, int nb, int E) {
    __shared__ int s[1024];
    int t = threadIdx.x;
    int v = (t < nb) ? bcount[t] : 0;
    s[t] = v;
    __syncthreads();
    for (int off = 1; off < 1024; off <<= 1) {
        int u = (t >= off) ? s[t - off] : 0;
        __syncthreads();
        s[t] += u;
        __syncthreads();
    }
    if (t < nb) { int ex = s[t] - v; bptr[t] = ex; bcur[t] = ex; }
    if (t == 0) bptr[nb] = E;
}

// ---------------- bin edges into bucket runs (block-level reservation) ----
__global__ __launch_bounds__(256) void k_bin(const int* __restrict__ src,
                                             const int* __restrict__ dst,
                                             int* __restrict__ bcur,
                                             unsigned* __restrict__ pairs,
                                             int E, int nb) {
    __shared__ int h[1024];     // local counts
    __shared__ int base[1024];  // reserved cursors
    for (int i = threadIdx.x; i < nb; i += 256) h[i] = 0;
    __syncthreads();

    int e0 = blockIdx.x * 256 * BIN_EPT;
    unsigned u[BIN_EPT];
    int cnt = 0;
#pragma unroll
    for (int j = 0; j < BIN_EPT; j++) {
        int e = e0 + j * 256 + threadIdx.x;
        if (e < E) {
            int d = dst[e];
            u[j] = ((unsigned)d << 16) | (unsigned)src[e];
            atomicAdd(&h[d >> BSH], 1);
            cnt = j + 1;
        }
    }
    __syncthreads();
    for (int i = threadIdx.x; i < nb; i += 256) {
        int c = h[i];
        base[i] = c ? atomicAdd(&bcur[i], c) : 0;
    }
    __syncthreads();
#pragma unroll
    for (int j = 0; j < BIN_EPT; j++) {
        if (j < cnt) {
            int pos = atomicAdd(&base[u[j] >> 22], 1);
            pairs[pos] = u[j];
        }
    }
}

// ---- per-bucket: row_ptr, dinv, CSR col fill in src-tile order ----------
__global__ __launch_bounds__(256) void k_fill2(const unsigned* __restrict__ pairs,
                                               const int* __restrict__ bptr,
                                               int* __restrict__ row_ptr,
                                               float* __restrict__ dinv,
                                               int* __restrict__ col,
                                               int N, int nb, int E) {
    __shared__ unsigned sp[STAGE];
    __shared__ int lcnt[64 * FT];   // counts, then running cursors
    int b = blockIdx.x;
    int node0 = b << BSH;
    int beg = bptr[b], end = bptr[b + 1];
    int cnt = end - beg;
    bool useStage = (cnt <= STAGE);

    for (int i = threadIdx.x; i < 64 * FT; i += 256) lcnt[i] = 0;
    __syncthreads();

    // pass A: (stage +) count per (node, src-tile)
    for (int i = threadIdx.x; i < cnt; i += 256) {
        unsigned u = pairs[beg + i];
        if (useStage) sp[i] = u;
        atomicAdd(&lcnt[((u >> 16) & 63) * FT + ((u & 0xffffu) >> FSH)], 1);
    }
    __syncthreads();

    // wave 0: per-node totals, wave-scan, write row_ptr/dinv, tile cursors
    if (threadIdx.x < 64) {
        int t = threadIdx.x;
        int c[FT]; int sum = 0;
#pragma unroll
        for (int f = 0; f < FT; f++) { c[f] = lcnt[t * FT + f]; sum += c[f]; }
        int x = sum;
#pragma unroll
        for (int off = 1; off < 64; off <<= 1) {
            int y = __shfl_up(x, off, 64);
            if (t >= off) x += y;
        }
        int nodebase = beg + x - sum;   // exclusive in-bucket prefix
        int node = node0 + t;
        if (node < N) {
            row_ptr[node] = nodebase;
            dinv[node] = rsqrtf((float)sum + 1.0f);
        }
        int run = nodebase;
#pragma unroll
        for (int f = 0; f < FT; f++) { lcnt[t * FT + f] = run; run += c[f]; }
        if (b == nb - 1 && t == 0) row_ptr[N] = E;
    }
    __syncthreads();

    // pass B: place
    for (int i = threadIdx.x; i < cnt; i += 256) {
        unsigned u = useStage ? sp[i] : pairs[beg + i];
        unsigned s = u & 0xffffu;
        int pos = atomicAdd(&lcnt[((u >> 16) & 63) * FT + (s >> FSH)], 1);
        col[pos] = (int)s;
    }
}

// ---------------- W -> fragment-ordered bf16 hi/lo (both layers) --------
__global__ __launch_bounds__(256) void k_wfrag2(const float* __restrict__ W1,
                                                const float* __restrict__ W2,
                                                short* __restrict__ Bh1,
                                                short* __restrict__ Bl1,
                                                short* __restrict__ Bh2,
                                                short* __restrict__ Bl2,
                                                int* __restrict__ bcount, int nb) {
    int idx = blockIdx.x * 256 + threadIdx.x;   // 0..32767
    if (idx < nb) bcount[idx] = 0;
    const float* W = (idx < 16384) ? W1 : W2;
    short* Bh = (idx < 16384) ? Bh1 : Bh2;
    short* Bl = (idx < 16384) ? Bl1 : Bl2;
    int id = idx & 16383;
    int j  = id & 7;
    int l  = (id >> 3) & 63;
    int ks = (id >> 9) & 3;
    int nt = id >> 11;
    int k   = ks * 32 + ((l >> 4) * 8) + j;
    int c   = nt * 16 + (l & 15);
    float w = W[k * 128 + c];
    short h = bf16h(w);
    Bh[id] = h;
    Bl[id] = bf16h(w - bf16f(h));
}

// ---------------- MFMA GEMM: H' = dinv * (X @ W), fp16 out --------------
__device__ __forceinline__ void load8(const float* p, float* v) {
    float4 a = *(const float4*)p;
    float4 b = *(const float4*)(p + 4);
    v[0] = a.x; v[1] = a.y; v[2] = a.z; v[3] = a.w;
    v[4] = b.x; v[5] = b.y; v[6] = b.z; v[7] = b.w;
}
__device__ __forceinline__ void load8(const __half* p, float* v) {
    float4 a = *(const float4*)p;   // 8 halves
    const __half2* h = (const __half2*)&a;
#pragma unroll
    for (int i = 0; i < 4; i++) {
        float2 f = __half22float2(h[i]);
        v[2 * i] = f.x; v[2 * i + 1] = f.y;
    }
}

template <typename T>
__global__ __launch_bounds__(256) void k_mm(const T* __restrict__ X,
                                            const short* __restrict__ Bhp,
                                            const short* __restrict__ Blp,
                                            const float* __restrict__ dinv,
                                            __half* __restrict__ Hh, int N) {
    int gw   = (blockIdx.x * 256 + threadIdx.x) >> 6;
    int lane = threadIdx.x & 63;
    int row0 = gw * 16;
    if (row0 >= N) return;

    int arow = row0 + (lane & 15);
    if (arow >= N) arow = N - 1;           // duplicate load; rows >= N not stored
    const T* Xp = X + (size_t)arow * DIM + ((lane >> 4) * 8);

    bf16x8 Ah[4], Al[4];
#pragma unroll
    for (int ks = 0; ks < 4; ks++) {
        float v[8];
        load8(Xp + ks * 32, v);
        bf16x8 h, lo;
#pragma unroll
        for (int j = 0; j < 8; j++) {
            short hh = bf16h(v[j]);
            h[j] = hh;
            lo[j] = bf16h(v[j] - bf16f(hh));
        }
        Ah[ks] = h;
        Al[ks] = lo;
    }

    const bf16x8* BH = (const bf16x8*)Bhp;
    const bf16x8* BL = (const bf16x8*)Blp;

    f32x4 acc[8];
#pragma unroll
    for (int nt = 0; nt < 8; nt++) {
        f32x4 c = {0.f, 0.f, 0.f, 0.f};
#pragma unroll
        for (int ks = 0; ks < 4; ks++) {
            bf16x8 bh = BH[(nt * 4 + ks) * 64 + lane];
            bf16x8 bl = BL[(nt * 4 + ks) * 64 + lane];
            c = __builtin_amdgcn_mfma_f32_16x16x32_bf16(Ah[ks], bh, c, 0, 0, 0);
            c = __builtin_amdgcn_mfma_f32_16x16x32_bf16(Al[ks], bh, c, 0, 0, 0);
            c = __builtin_amdgcn_mfma_f32_16x16x32_bf16(Ah[ks], bl, c, 0, 0, 0);
        }
        acc[nt] = c;
    }

    // C/D: col = lane&15 (+nt*16), row = (lane>>4)*4 + reg   [m89/m91]
    int rb = row0 + ((lane >> 4) * 4);
    int cb = lane & 15;
#pragma unroll
    for (int r = 0; r < 4; r++) {
        if (rb + r < N) {
            float dv = dinv[rb + r];
            __half* out = Hh + (size_t)(rb + r) * DIM + cb;
#pragma unroll
            for (int nt = 0; nt < 8; nt++)
                out[nt * 16] = __float2half(acc[nt][r] * dv);
        }
    }
}

// ---------------- aggregation core: one wave per dst node ----------------
// 16-deep gather batches: all 16 H-row loads issued before any conversion,
// maximizing outstanding memory ops per wave.
__device__ __forceinline__ float2 agg_row(const __half2* __restrict__ Hh,
                                          const int* __restrict__ row_ptr,
                                          const int* __restrict__ col,
                                          const float* __restrict__ dinv,
                                          const float* __restrict__ B,
                                          int wid, int lane) {
    int beg = __builtin_amdgcn_readfirstlane(row_ptr[wid]);
    int end = __builtin_amdgcn_readfirstlane(row_ptr[wid + 1]);
    const __half2* Hl = Hh + lane;  // row s -> Hl[s*64]
    float2 s0f = __half22float2(Hl[(size_t)wid * 64]);  // self (H'[d])
    float ax = s0f.x, ay = s0f.y;
    float bx = 0.f, by = 0.f, cx = 0.f, cy = 0.f, dx = 0.f, dy = 0.f;

    int e = beg;
    for (; e + 16 <= end; e += 16) {
        __half2 g[16];
#pragma unroll
        for (int j = 0; j < 16; j++) g[j] = Hl[(size_t)col[e + j] * 64];
#pragma unroll
        for (int j = 0; j < 16; j += 4) {
            float2 f0 = __half22float2(g[j + 0]);
            float2 f1 = __half22float2(g[j + 1]);
            float2 f2 = __half22float2(g[j + 2]);
            float2 f3 = __half22float2(g[j + 3]);
            ax += f0.x; ay += f0.y;  bx += f1.x; by += f1.y;
            cx += f2.x; cy += f2.y;  dx += f3.x; dy += f3.y;
        }
    }
    for (; e + 8 <= end; e += 8) {
        __half2 g[8];
#pragma unroll
        for (int j = 0; j < 8; j++) g[j] = Hl[(size_t)col[e + j] * 64];
#pragma unroll
        for (int j = 0; j < 8; j += 4) {
            float2 f0 = __half22float2(g[j + 0]);
            float2 f1 = __half22float2(g[j + 1]);
            float2 f2 = __half22float2(g[j + 2]);
            float2 f3 = __half22float2(g[j + 3]);
            ax += f0.x; ay += f0.y;  bx += f1.x; by += f1.y;
            cx += f2.x; cy += f2.y;  dx += f3.x; dy += f3.y;
        }
    }
    for (; e + 4 <= end; e += 4) {
        __half2 g0 = Hl[(size_t)col[e + 0] * 64];
        __half2 g1 = Hl[(size_t)col[e + 1] * 64];
        __half2 g2 = Hl[(size_t)col[e + 2] * 64];
        __half2 g3 = Hl[(size_t)col[e + 3] * 64];
        float2 f0 = __half22float2(g0), f1 = __half22float2(g1);
        float2 f2 = __half22float2(g2), f3 = __half22float2(g3);
        ax += f0.x; ay += f0.y;  bx += f1.x; by += f1.y;
        cx += f2.x; cy += f2.y;  dx += f3.x; dy += f3.y;
    }
    for (; e < end; e++) {
        float2 f = __half22float2(Hl[(size_t)col[e] * 64]);
        ax += f.x; ay += f.y;
    }
    ax += bx + cx + dx;
    ay += by + cy + dy;

    float di = dinv[wid];
    float2 b = *(const float2*)(B + lane * 2);
    return make_float2(fmaf(di, ax, b.x), fmaf(di, ay, b.y));
}

// layer-1: write relu'd fp16 row
__global__ __launch_bounds__(256) void k_agg(const __half2* __restrict__ Hh,
                                             const int* __restrict__ row_ptr,
                                             const int* __restrict__ col,
                                             const float* __restrict__ dinv,
                                             const float* __restrict__ B,
                                             __half2* __restrict__ O, int N) {
    int wid = (blockIdx.x * 256 + threadIdx.x) >> 6;
    int lane = threadIdx.x & 63;
    if (wid >= N) return;
    float2 r = agg_row(Hh, row_ptr, col, dinv, B, wid, lane);
    O[(size_t)wid * 64 + lane] = __floats2half2_rn(fmaxf(r.x, 0.f), fmaxf(r.y, 0.f));
}

// layer-2 + readout fused: out[n] = dot(relu(row), Wr) + br
__global__ __launch_bounds__(256) void k_agg_out(const __half2* __restrict__ Hh,
                                                 const int* __restrict__ row_ptr,
                                                 const int* __restrict__ col,
                                                 const float* __restrict__ dinv,
                                                 const float* __restrict__ B,
                                                 const float* __restrict__ Wr,
                                                 const float* __restrict__ br,
                                                 float* __restrict__ out, int N) {
    int wid = (blockIdx.x * 256 + threadIdx.x) >> 6;
    int lane = threadIdx.x & 63;
    if (wid >= N) return;
    float2 r = agg_row(Hh, row_ptr, col, dinv, B, wid, lane);
    float2 w = *(const float2*)(Wr + lane * 2);
    float v = fmaxf(r.x, 0.f) * w.x + fmaxf(r.y, 0.f) * w.y;
#pragma unroll
    for (int off = 32; off > 0; off >>= 1) v += __shfl_down(v, off, 64);
    if (lane == 0) out[wid] = v + br[0];
}

extern "C" void kernel_launch(void* const* d_in, const int* in_sizes, int n_in,
                              void* d_out, int out_size, void* d_ws, size_t ws_size,
                              hipStream_t stream) {
    const float* x  = (const float*)d_in[0];
    const int*   ei = (const int*)d_in[1];
    const float* W1 = (const float*)d_in[2];
    const float* b1 = (const float*)d_in[3];
    const float* W2 = (const float*)d_in[4];
    const float* b2 = (const float*)d_in[5];
    const float* Wr = (const float*)d_in[6];
    const float* br = (const float*)d_in[7];

    const int N = in_sizes[0] / DIM;
    const int E = in_sizes[1] / 2;
    const int* src = ei;
    const int* dst = ei + E;
    const int NB = (N + 63) >> BSH;  // buckets of 64 nodes

    char* p = (char*)d_ws;
    auto alloc = [&](size_t bytes) -> void* {
        void* r = (void*)p;
        p += (bytes + 255) & ~(size_t)255;
        return r;
    };
    __half*   Hh      = (__half*)alloc((size_t)N * DIM * 2);   // fp16 H'
    __half*   A1      = (__half*)alloc((size_t)N * DIM * 2);   // layer-1 out fp16
    float*    dinv    = (float*)alloc((size_t)N * 4);
    int*      row_ptr = (int*)alloc((size_t)(N + 1) * 4);
    int*      bcount  = (int*)alloc((size_t)NB * 4);
    int*      bptr    = (int*)alloc((size_t)(NB + 1) * 4);
    int*      bcur    = (int*)alloc((size_t)NB * 4);
    unsigned* pairs   = (unsigned*)alloc((size_t)E * 4);
    int*      col     = (int*)alloc((size_t)E * 4);
    short*    Bh1     = (short*)alloc(16384 * 2);
    short*    Bl1     = (short*)alloc(16384 * 2);
    short*    Bh2     = (short*)alloc(16384 * 2);
    short*    Bl2     = (short*)alloc(16384 * 2);
    (void)ws_size; (void)n_in;

    // W frag prep + bcount zero-init (must precede k_hist; same stream)
    k_wfrag2<<<128, 256, 0, stream>>>(W1, W2, Bh1, Bl1, Bh2, Bl2, bcount, NB);

    // CSR build
    k_hist<<<256, 256, 0, stream>>>(dst, bcount, E, NB);
    k_bscan<<<1, 1024, 0, stream>>>(bcount, bptr, bcur, NB, E);
    const int binb = (E + 256 * BIN_EPT - 1) / (256 * BIN_EPT);
    k_bin<<<binb, 256, 0, stream>>>(src, dst, bcur, pairs, E, NB);
    k_fill2<<<NB, 256, 0, stream>>>(pairs, bptr, row_ptr, dinv, col, N, NB, E);

    const int mmb = ((N + 15) / 16 + 3) / 4;   // waves of 16 rows, 4 waves/block
    const int ab  = (N * 64 + 255) / 256;

    k_mm<float><<<mmb, 256, 0, stream>>>(x, Bh1, Bl1, dinv, Hh, N);
    k_agg<<<ab, 256, 0, stream>>>((const __half2*)Hh, row_ptr, col, dinv, b1,
                                  (__half2*)A1, N);
    k_mm<__half><<<mmb, 256, 0, stream>>>(A1, Bh2, Bl2, dinv, Hh, N);
    k_agg_out<<<ab, 256, 0, stream>>>((const __half2*)Hh, row_ptr, col, dinv, b2,
                                      Wr, br, (float*)d_out, N);
}

// Round 9
// 131.458 us; speedup vs baseline: 2.8895x; 1.0464x over previous
//
#include <hip/hip_runtime.h>
#include <hip/hip_fp16.h>
#include <cstdint>
#include <cstddef>

// GCN refold: H'_l = dinv * (X_l @ W_l)  (fp16), layer out = relu(dinv*(sum+self)+b)
// GEMM via MFMA bf16 hi/lo split. CSR build: prep(wfrag+hist-partials) ->
// bscan(sum+scan) -> bin(int4 loads, block-local scatter) -> fill2 (LDS-local).
// Requires N < 65536.

constexpr int DIM = 128;
#define BSH 6                 // 64 nodes per bucket
#define HB 128                // hist blocks (also wfrag: 128*256 = 32768 threads)
#define BIN_EPT 12            // edges per thread in k_bin (multiple of 4)
#define FT 8                  // src tiles (in-row CSR order; harmless)
#define FSH 13
#define STAGE 2048            // LDS edge stage per bucket

typedef __attribute__((ext_vector_type(8))) short bf16x8;   // 8 bf16 (4 VGPRs)
typedef __attribute__((ext_vector_type(4))) float f32x4;

__device__ __forceinline__ short bf16h(float x) {
    unsigned u = __float_as_uint(x);
    return (short)((u + 0x7FFFu + ((u >> 16) & 1u)) >> 16);  // RNE bf16
}
__device__ __forceinline__ float bf16f(short h) {
    return __uint_as_float(((unsigned)(unsigned short)h) << 16);
}

// ---- prep: W->bf16 hi/lo frags (both layers) + hist partials (no atomics) --
// Frag layout (16x16x32 B-operand): id = ((nt*4+ks)*64 + lane)*8 + j
//   element = W[(ks*32 + (lane>>4)*8 + j)*128 + nt*16 + (lane&15)]
__global__ __launch_bounds__(256) void k_prep(const float* __restrict__ W1,
                                              const float* __restrict__ W2,
                                              short* __restrict__ Bh1,
                                              short* __restrict__ Bl1,
                                              short* __restrict__ Bh2,
                                              short* __restrict__ Bl2,
                                              const int* __restrict__ dst,
                                              int* __restrict__ h_part,
                                              int E, int nb) {
    // part 1: weight fragments (exactly HB*256 = 32768 threads, 2 layers)
    {
        int idx = blockIdx.x * 256 + threadIdx.x;
        const float* W = (idx < 16384) ? W1 : W2;
        short* Bh = (idx < 16384) ? Bh1 : Bh2;
        short* Bl = (idx < 16384) ? Bl1 : Bl2;
        int id = idx & 16383;
        int j  = id & 7;
        int l  = (id >> 3) & 63;
        int ks = (id >> 9) & 3;
        int nt = id >> 11;
        int k  = ks * 32 + ((l >> 4) * 8) + j;
        int c  = nt * 16 + (l & 15);
        float w = W[k * 128 + c];
        short h = bf16h(w);
        Bh[id] = h;
        Bl[id] = bf16h(w - bf16f(h));
    }
    // part 2: bucket histogram partials (LDS, written per block — no atomics)
    __shared__ int h[1024];
    for (int i = threadIdx.x; i < 1024; i += 256) h[i] = 0;
    __syncthreads();
    int E4 = E >> 2;
    for (int v = blockIdx.x * 256 + threadIdx.x; v < E4; v += HB * 256) {
        int4 d4 = *(const int4*)(dst + v * 4);
        atomicAdd(&h[d4.x >> BSH], 1);
        atomicAdd(&h[d4.y >> BSH], 1);
        atomicAdd(&h[d4.z >> BSH], 1);
        atomicAdd(&h[d4.w >> BSH], 1);
    }
    if (blockIdx.x == 0 && threadIdx.x < (E & 3))
        atomicAdd(&h[dst[E4 * 4 + threadIdx.x] >> BSH], 1);
    __syncthreads();
    for (int i = threadIdx.x; i < nb; i += 256)
        h_part[blockIdx.x * 1024 + i] = h[i];
}

// ---- bucket scan: sum HB partials per bucket, exclusive scan ------------
__global__ __launch_bounds__(1024) void k_bscan(const int* __restrict__ h_part,
                                                int* __restrict__ bptr,
                                                int* __restrict__ bcur, int nb, int E) {
    __shared__ int s[1024];
    int t = threadIdx.x;
    int v = 0;
    if (t < nb)
        for (int b = 0; b < HB; b++) v += h_part[b * 1024 + t];
    s[t] = v;
    __syncthreads();
    for (int off = 1; off < 1024; off <<= 1) {
        int u = (t >= off) ? s[t - off] : 0;
        __syncthreads();
        s[t] += u;
        __syncthreads();
    }
    if (t < nb) { int ex = s[t] - v; bptr[t] = ex; bcur[t] = ex; }
    if (t == 0) bptr[nb] = E;
}

// ---- bin edges into bucket runs (block-level reservation, int4 loads) ----
__global__ __launch_bounds__(256) void k_bin(const int* __restrict__ src,
                                             const int* __restrict__ dst,
                                             int* __restrict__ bcur,
                                             unsigned* __restrict__ pairs,
                                             int E, int nb) {
    __shared__ int h[1024];     // local counts
    __shared__ int base[1024];  // reserved cursors
    for (int i = threadIdx.x; i < nb; i += 256) h[i] = 0;
    __syncthreads();

    int e0 = blockIdx.x * 256 * BIN_EPT;
    unsigned u[BIN_EPT];
    int cnt = 0;
#pragma unroll
    for (int j = 0; j < BIN_EPT / 4; j++) {
        int b4 = e0 + j * 1024 + threadIdx.x * 4;
        if (b4 + 4 <= E) {
            int4 s4 = *(const int4*)(src + b4);
            int4 d4 = *(const int4*)(dst + b4);
            u[4 * j + 0] = ((unsigned)d4.x << 16) | (unsigned)s4.x;
            u[4 * j + 1] = ((unsigned)d4.y << 16) | (unsigned)s4.y;
            u[4 * j + 2] = ((unsigned)d4.z << 16) | (unsigned)s4.z;
            u[4 * j + 3] = ((unsigned)d4.w << 16) | (unsigned)s4.w;
            atomicAdd(&h[d4.x >> BSH], 1);
            atomicAdd(&h[d4.y >> BSH], 1);
            atomicAdd(&h[d4.z >> BSH], 1);
            atomicAdd(&h[d4.w >> BSH], 1);
            cnt = 4 * j + 4;
        } else {
#pragma unroll
            for (int k = 0; k < 4; k++) {
                int e = b4 + k;
                if (e < E) {
                    int d = dst[e];
                    u[4 * j + k] = ((unsigned)d << 16) | (unsigned)src[e];
                    atomicAdd(&h[d >> BSH], 1);
                    cnt = 4 * j + k + 1;
                }
            }
        }
    }
    __syncthreads();
    for (int i = threadIdx.x; i < nb; i += 256) {
        int c = h[i];
        base[i] = c ? atomicAdd(&bcur[i], c) : 0;
    }
    __syncthreads();
#pragma unroll
    for (int j = 0; j < BIN_EPT; j++) {
        if (j < cnt) {
            int pos = atomicAdd(&base[u[j] >> 22], 1);
            pairs[pos] = u[j];
        }
    }
}

// ---- per-bucket: row_ptr, dinv, CSR col fill in src-tile order ----------
__global__ __launch_bounds__(256) void k_fill2(const unsigned* __restrict__ pairs,
                                               const int* __restrict__ bptr,
                                               int* __restrict__ row_ptr,
                                               float* __restrict__ dinv,
                                               int* __restrict__ col,
                                               int N, int nb, int E) {
    __shared__ unsigned sp[STAGE];
    __shared__ int lcnt[64 * FT];   // counts, then running cursors
    int b = blockIdx.x;
    int node0 = b << BSH;
    int beg = bptr[b], end = bptr[b + 1];
    int cnt = end - beg;
    bool useStage = (cnt <= STAGE);

    for (int i = threadIdx.x; i < 64 * FT; i += 256) lcnt[i] = 0;
    __syncthreads();

    // pass A: (stage +) count per (node, src-tile)
    for (int i = threadIdx.x; i < cnt; i += 256) {
        unsigned u = pairs[beg + i];
        if (useStage) sp[i] = u;
        atomicAdd(&lcnt[((u >> 16) & 63) * FT + ((u & 0xffffu) >> FSH)], 1);
    }
    __syncthreads();

    // wave 0: per-node totals, wave-scan, write row_ptr/dinv, tile cursors
    if (threadIdx.x < 64) {
        int t = threadIdx.x;
        int c[FT]; int sum = 0;
#pragma unroll
        for (int f = 0; f < FT; f++) { c[f] = lcnt[t * FT + f]; sum += c[f]; }
        int x = sum;
#pragma unroll
        for (int off = 1; off < 64; off <<= 1) {
            int y = __shfl_up(x, off, 64);
            if (t >= off) x += y;
        }
        int nodebase = beg + x - sum;   // exclusive in-bucket prefix
        int node = node0 + t;
        if (node < N) {
            row_ptr[node] = nodebase;
            dinv[node] = rsqrtf((float)sum + 1.0f);
        }
        int run = nodebase;
#pragma unroll
        for (int f = 0; f < FT; f++) { lcnt[t * FT + f] = run; run += c[f]; }
        if (b == nb - 1 && t == 0) row_ptr[N] = E;
    }
    __syncthreads();

    // pass B: place
    for (int i = threadIdx.x; i < cnt; i += 256) {
        unsigned u = useStage ? sp[i] : pairs[beg + i];
        unsigned s = u & 0xffffu;
        int pos = atomicAdd(&lcnt[((u >> 16) & 63) * FT + (s >> FSH)], 1);
        col[pos] = (int)s;
    }
}

// ---------------- MFMA GEMM: H' = dinv * (X @ W), fp16 out --------------
__device__ __forceinline__ void load8(const float* p, float* v) {
    float4 a = *(const float4*)p;
    float4 b = *(const float4*)(p + 4);
    v[0] = a.x; v[1] = a.y; v[2] = a.z; v[3] = a.w;
    v[4] = b.x; v[5] = b.y; v[6] = b.z; v[7] = b.w;
}
__device__ __forceinline__ void load8(const __half* p, float* v) {
    float4 a = *(const float4*)p;   // 8 halves
    const __half2* h = (const __half2*)&a;
#pragma unroll
    for (int i = 0; i < 4; i++) {
        float2 f = __half22float2(h[i]);
        v[2 * i] = f.x; v[2 * i + 1] = f.y;
    }
}

template <typename T>
__global__ __launch_bounds__(256) void k_mm(const T* __restrict__ X,
                                            const short* __restrict__ Bhp,
                                            const short* __restrict__ Blp,
                                            const float* __restrict__ dinv,
                                            __half* __restrict__ Hh, int N) {
    int gw   = (blockIdx.x * 256 + threadIdx.x) >> 6;
    int lane = threadIdx.x & 63;
    int row0 = gw * 16;
    if (row0 >= N) return;

    int arow = row0 + (lane & 15);
    if (arow >= N) arow = N - 1;           // duplicate load; rows >= N not stored
    const T* Xp = X + (size_t)arow * DIM + ((lane >> 4) * 8);

    bf16x8 Ah[4], Al[4];
#pragma unroll
    for (int ks = 0; ks < 4; ks++) {
        float v[8];
        load8(Xp + ks * 32, v);
        bf16x8 h, lo;
#pragma unroll
        for (int j = 0; j < 8; j++) {
            short hh = bf16h(v[j]);
            h[j] = hh;
            lo[j] = bf16h(v[j] - bf16f(hh));
        }
        Ah[ks] = h;
        Al[ks] = lo;
    }

    const bf16x8* BH = (const bf16x8*)Bhp;
    const bf16x8* BL = (const bf16x8*)Blp;

    f32x4 acc[8];
#pragma unroll
    for (int nt = 0; nt < 8; nt++) {
        f32x4 c = {0.f, 0.f, 0.f, 0.f};
#pragma unroll
        for (int ks = 0; ks < 4; ks++) {
            bf16x8 bh = BH[(nt * 4 + ks) * 64 + lane];
            bf16x8 bl = BL[(nt * 4 + ks) * 64 + lane];
            c = __builtin_amdgcn_mfma_f32_16x16x32_bf16(Ah[ks], bh, c, 0, 0, 0);
            c = __builtin_amdgcn_mfma_f32_16x16x32_bf16(Al[ks], bh, c, 0, 0, 0);
            c = __builtin_amdgcn_mfma_f32_16x16x32_bf16(Ah[ks], bl, c, 0, 0, 0);
        }
        acc[nt] = c;
    }

    // C/D: col = lane&15 (+nt*16), row = (lane>>4)*4 + reg   [m89/m91]
    int rb = row0 + ((lane >> 4) * 4);
    int cb = lane & 15;
#pragma unroll
    for (int r = 0; r < 4; r++) {
        if (rb + r < N) {
            float dv = dinv[rb + r];
            __half* out = Hh + (size_t)(rb + r) * DIM + cb;
#pragma unroll
            for (int nt = 0; nt < 8; nt++)
                out[nt * 16] = __float2half(acc[nt][r] * dv);
        }
    }
}

// ---------------- aggregation core: one wave per dst node ----------------
__device__ __forceinline__ float2 agg_row(const __half2* __restrict__ Hh,
                                          const int* __restrict__ row_ptr,
                                          const int* __restrict__ col,
                                          const float* __restrict__ dinv,
                                          const float* __restrict__ B,
                                          int wid, int lane) {
    int beg = __builtin_amdgcn_readfirstlane(row_ptr[wid]);
    int end = __builtin_amdgcn_readfirstlane(row_ptr[wid + 1]);
    const __half2* Hl = Hh + lane;  // row s -> Hl[s*64]
    float2 s0f = __half22float2(Hl[(size_t)wid * 64]);  // self (H'[d])
    float ax = s0f.x, ay = s0f.y;
    float bx = 0.f, by = 0.f, cx = 0.f, cy = 0.f, dx = 0.f, dy = 0.f;

    int e = beg;
    for (; e + 16 <= end; e += 16) {
        __half2 g[16];
#pragma unroll
        for (int j = 0; j < 16; j++) g[j] = Hl[(size_t)col[e + j] * 64];
#pragma unroll
        for (int j = 0; j < 16; j += 4) {
            float2 f0 = __half22float2(g[j + 0]);
            float2 f1 = __half22float2(g[j + 1]);
            float2 f2 = __half22float2(g[j + 2]);
            float2 f3 = __half22float2(g[j + 3]);
            ax += f0.x; ay += f0.y;  bx += f1.x; by += f1.y;
            cx += f2.x; cy += f2.y;  dx += f3.x; dy += f3.y;
        }
    }
    for (; e + 8 <= end; e += 8) {
        __half2 g[8];
#pragma unroll
        for (int j = 0; j < 8; j++) g[j] = Hl[(size_t)col[e + j] * 64];
#pragma unroll
        for (int j = 0; j < 8; j += 4) {
            float2 f0 = __half22float2(g[j + 0]);
            float2 f1 = __half22float2(g[j + 1]);
            float2 f2 = __half22float2(g[j + 2]);
            float2 f3 = __half22float2(g[j + 3]);
            ax += f0.x; ay += f0.y;  bx += f1.x; by += f1.y;
            cx += f2.x; cy += f2.y;  dx += f3.x; dy += f3.y;
        }
    }
    for (; e + 4 <= end; e += 4) {
        __half2 g0 = Hl[(size_t)col[e + 0] * 64];
        __half2 g1 = Hl[(size_t)col[e + 1] * 64];
        __half2 g2 = Hl[(size_t)col[e + 2] * 64];
        __half2 g3 = Hl[(size_t)col[e + 3] * 64];
        float2 f0 = __half22float2(g0), f1 = __half22float2(g1);
        float2 f2 = __half22float2(g2), f3 = __half22float2(g3);
        ax += f0.x; ay += f0.y;  bx += f1.x; by += f1.y;
        cx += f2.x; cy += f2.y;  dx += f3.x; dy += f3.y;
    }
    for (; e < end; e++) {
        float2 f = __half22float2(Hl[(size_t)col[e] * 64]);
        ax += f.x; ay += f.y;
    }
    ax += bx + cx + dx;
    ay += by + cy + dy;

    float di = dinv[wid];
    float2 b = *(const float2*)(B + lane * 2);
    return make_float2(fmaf(di, ax, b.x), fmaf(di, ay, b.y));
}

// layer-1: write relu'd fp16 row
__global__ __launch_bounds__(256) void k_agg(const __half2* __restrict__ Hh,
                                             const int* __restrict__ row_ptr,
                                             const int* __restrict__ col,
                                             const float* __restrict__ dinv,
                                             const float* __restrict__ B,
                                             __half2* __restrict__ O, int N) {
    int wid = (blockIdx.x * 256 + threadIdx.x) >> 6;
    int lane = threadIdx.x & 63;
    if (wid >= N) return;
    float2 r = agg_row(Hh, row_ptr, col, dinv, B, wid, lane);
    O[(size_t)wid * 64 + lane] = __floats2half2_rn(fmaxf(r.x, 0.f), fmaxf(r.y, 0.f));
}

// layer-2 + readout fused: out[n] = dot(relu(row), Wr) + br
__global__ __launch_bounds__(256) void k_agg_out(const __half2* __restrict__ Hh,
                                                 const int* __restrict__ row_ptr,
                                                 const int* __restrict__ col,
                                                 const float* __restrict__ dinv,
                                                 const float* __restrict__ B,
                                                 const float* __restrict__ Wr,
                                                 const float* __restrict__ br,
                                                 float* __restrict__ out, int N) {
    int wid = (blockIdx.x * 256 + threadIdx.x) >> 6;
    int lane = threadIdx.x & 63;
    if (wid >= N) return;
    float2 r = agg_row(Hh, row_ptr, col, dinv, B, wid, lane);
    float2 w = *(const float2*)(Wr + lane * 2);
    float v = fmaxf(r.x, 0.f) * w.x + fmaxf(r.y, 0.f) * w.y;
#pragma unroll
    for (int off = 32; off > 0; off >>= 1) v += __shfl_down(v, off, 64);
    if (lane == 0) out[wid] = v + br[0];
}

extern "C" void kernel_launch(void* const* d_in, const int* in_sizes, int n_in,
                              void* d_out, int out_size, void* d_ws, size_t ws_size,
                              hipStream_t stream) {
    const float* x  = (const float*)d_in[0];
    const int*   ei = (const int*)d_in[1];
    const float* W1 = (const float*)d_in[2];
    const float* b1 = (const float*)d_in[3];
    const float* W2 = (const float*)d_in[4];
    const float* b2 = (const float*)d_in[5];
    const float* Wr = (const float*)d_in[6];
    const float* br = (const float*)d_in[7];

    const int N = in_sizes[0] / DIM;
    const int E = in_sizes[1] / 2;
    const int* src = ei;
    const int* dst = ei + E;
    const int NB = (N + 63) >> BSH;  // buckets of 64 nodes

    char* p = (char*)d_ws;
    auto alloc = [&](size_t bytes) -> void* {
        void* r = (void*)p;
        p += (bytes + 255) & ~(size_t)255;
        return r;
    };
    __half*   Hh      = (__half*)alloc((size_t)N * DIM * 2);   // fp16 H'
    __half*   A1      = (__half*)alloc((size_t)N * DIM * 2);   // layer-1 out fp16
    float*    dinv    = (float*)alloc((size_t)N * 4);
    int*      row_ptr = (int*)alloc((size_t)(N + 1) * 4);
    int*      h_part  = (int*)alloc((size_t)HB * 1024 * 4);
    int*      bptr    = (int*)alloc((size_t)(NB + 1) * 4);
    int*      bcur    = (int*)alloc((size_t)NB * 4);
    unsigned* pairs   = (unsigned*)alloc((size_t)E * 4);
    int*      col     = (int*)alloc((size_t)E * 4);
    short*    Bh1     = (short*)alloc(16384 * 2);
    short*    Bl1     = (short*)alloc(16384 * 2);
    short*    Bh2     = (short*)alloc(16384 * 2);
    short*    Bl2     = (short*)alloc(16384 * 2);
    (void)ws_size; (void)n_in;

    // prep: W frags + hist partials
    k_prep<<<HB, 256, 0, stream>>>(W1, W2, Bh1, Bl1, Bh2, Bl2, dst, h_part, E, NB);
    k_bscan<<<1, 1024, 0, stream>>>(h_part, bptr, bcur, NB, E);
    const int binb = (E + 256 * BIN_EPT - 1) / (256 * BIN_EPT);
    k_bin<<<binb, 256, 0, stream>>>(src, dst, bcur, pairs, E, NB);
    k_fill2<<<NB, 256, 0, stream>>>(pairs, bptr, row_ptr, dinv, col, N, NB, E);

    const int mmb = ((N + 15) / 16 + 3) / 4;   // waves of 16 rows, 4 waves/block
    const int ab  = (N * 64 + 255) / 256;

    k_mm<float><<<mmb, 256, 0, stream>>>(x, Bh1, Bl1, dinv, Hh, N);
    k_agg<<<ab, 256, 0, stream>>>((const __half2*)Hh, row_ptr, col, dinv, b1,
                                  (__half2*)A1, N);
    k_mm<__half><<<mmb, 256, 0, stream>>>(A1, Bh2, Bl2, dinv, Hh, N);
    k_agg_out<<<ab, 256, 0, stream>>>((const __half2*)Hh, row_ptr, col, dinv, b2,
                                      Wr, br, (float*)d_out, N);
}